// Round 11
// baseline (906.284 us; speedup 1.0000x reference)
//
#include <hip/hip_runtime.h>
#include <math.h>

// ---------------------------------------------------------------------------
// OneRecTokenizer. B=64 S=512 MM=1024 HID=512 T=4 NL=4 NHEAD=8 DH=64 RQ_L=3 CB=256
// Round 11: round-10 base +
//  (a) proj converted to pre-split A (mm -> bf16 hi/lo pass) + global_load_lds
//      staging (kills the 16-way ds_write bank conflict + split2 VALU),
//  (b) xT written directly from proj epilogue (transpose_x kernel eliminated),
//  (c) ws aliasing: mm-split region reused for folded weights (preps after proj).
// bf16x2 3-pass split everywhere: A*B ~= Ah*Bh + Ah*Bl + Al*Bh (rel err ~2^-17).
// ---------------------------------------------------------------------------

typedef __attribute__((ext_vector_type(8))) short   s16x8;
typedef __attribute__((ext_vector_type(8))) __bf16  bf16x8;
typedef __attribute__((ext_vector_type(4))) float   f32x4;

__device__ __forceinline__ void split2(float v, unsigned short& hi, unsigned short& lo) {
    unsigned u = __builtin_bit_cast(unsigned, v);
    hi = (unsigned short)(u >> 16);
    float hf = __builtin_bit_cast(float, u & 0xffff0000u);
    float l = v - hf;
    unsigned ul = __builtin_bit_cast(unsigned, l);
    lo = (unsigned short)((ul + 0x7fffu + ((ul >> 16) & 1u)) >> 16);
}

__device__ __forceinline__ f32x4 mfma16(bf16x8 a, bf16x8 b, f32x4 c) {
    return __builtin_amdgcn_mfma_f32_16x16x32_bf16(a, b, c, 0, 0, 0);
}

__device__ __forceinline__ void gload16(const void* g, void* l) {
    __builtin_amdgcn_global_load_lds(
        (const __attribute__((address_space(1))) unsigned*)g,
        (__attribute__((address_space(3))) unsigned*)l, 16, 0, 0);
}

__device__ __forceinline__ bf16x8 bc16(const unsigned short* p) {
    return __builtin_bit_cast(bf16x8, *(const s16x8*)p);
}

// ---------------------------------------------------------------------------
// Unified bf16x2 3-pass MFMA GEMM. BN=128. AMODE 0: A split bf16 (BM 16/32/128,
// gload_lds). OMODE 0 fp32 / 1 split-bf16. IDX 0 plain, 1 A-scatter.
// XTW: also write xT[b][c][s] (packed uint2) from the accumulators (proj).
// ---------------------------------------------------------------------------
template<int BM, int FM, int FN, int WR, int WC, int AMODE, int OMODE,
         int IDX, bool GELU, bool SWZ, bool XTW>
__global__ __launch_bounds__(256)
void mfma_gemm(const void* __restrict__ Ah_, const void* __restrict__ Al_,
               const unsigned short* __restrict__ Bh_, const unsigned short* __restrict__ Bl_,
               const float* __restrict__ bias,
               void* __restrict__ Ch_, void* __restrict__ Cl_,
               int K, int lda, int ldb, int ldc,
               long strA, long strB, long strC,
               unsigned short* __restrict__ xTh_, unsigned short* __restrict__ xTl_)
{
    constexpr int BHALF = 8192;
    constexpr int AHALF = 2 * BM * 32;
    __shared__ __align__(16) unsigned short sA[2 * AHALF];
    __shared__ __align__(16) unsigned short sB[2 * BHALF];

    int bx = blockIdx.x, by = blockIdx.y;
    if constexpr (SWZ) {
        int nb = gridDim.x * gridDim.y;
        int h  = bx + gridDim.x * by;
        int orig = (h & 7) * (nb >> 3) + (h >> 3);
        bx = orig % gridDim.x; by = orig / gridDim.x;
    }
    const int tid = threadIdx.x, z = blockIdx.z;
    const int m0 = by * BM, n0 = bx * 128;
    const int lane = tid & 63, w = tid >> 6;
    const int wr = w / WC, wc = w % WC;

    const unsigned short* Ah = (const unsigned short*)Ah_ + (long)z * strA;
    const unsigned short* Al = (const unsigned short*)Al_ + (long)z * strA;
    const unsigned short* Bh = Bh_ + (long)z * strB;
    const unsigned short* Bl = Bl_ + (long)z * strB;

    auto stageB = [&](int buf, int k0) {
#pragma unroll
        for (int i = 0; i < 4; i++) {
            const int c = tid + 256 * i;
            const int p = c >> 9, cc = c & 511, r = cc >> 2, sl = cc & 3;
            const int fs = (r + (r >> 2)) & 3;
            const unsigned short* g = (p ? Bl : Bh) + (long)(n0 + r) * ldb + k0 + ((sl ^ fs)) * 8;
            gload16(g, sB + buf * BHALF + p * 4096 + r * 32 + sl * 8);
        }
    };
    auto stageA = [&](int buf, int k0) {
        if constexpr (BM == 128) {
#pragma unroll
            for (int i = 0; i < 4; i++) {
                const int c = tid + 256 * i;
                const int p = c >> 9, cc = c & 511, r = cc >> 2, sl = cc & 3;
                const int fs = (r + (r >> 2)) & 3;
                const unsigned short* g = (p ? Al : Ah) + (long)(m0 + r) * lda + k0 + ((sl ^ fs)) * 8;
                gload16(g, sA + buf * AHALF + p * (BM * 32) + r * 32 + sl * 8);
            }
        } else if constexpr (BM == 32) {
            const int p = tid >> 7, c = tid & 127, r = c >> 2, sl = c & 3;
            const int fs = (r + (r >> 2)) & 3;
            const unsigned short* g = (p ? Al : Ah) + (long)(m0 + r) * lda + k0 + ((sl ^ fs)) * 8;
            gload16(g, sA + buf * AHALF + p * (BM * 32) + r * 32 + sl * 8);
        } else {  // BM == 16
            if (tid < 128) {
                const int p = tid >> 6, c = tid & 63, r = c >> 2, sl = c & 3;
                const int fs = (r + (r >> 2)) & 3;
                const unsigned short* g = (p ? Al : Ah) + (long)(m0 + r) * lda + k0 + ((sl ^ fs)) * 8;
                gload16(g, sA + buf * AHALF + p * (BM * 32) + r * 32 + sl * 8);
            }
        }
    };

    f32x4 acc[FM][FN];
#pragma unroll
    for (int i = 0; i < FM; i++)
#pragma unroll
        for (int j = 0; j < FN; j++) acc[i][j] = f32x4{0.f, 0.f, 0.f, 0.f};

    const int NT = K / 32;
    int buf = 0;
    stageB(0, 0);
    stageA(0, 0);
    __syncthreads();

    const int li = lane & 15, ks = lane >> 4;

    for (int kt = 0; kt < NT; kt++) {
        if (kt + 1 < NT) { stageB(buf ^ 1, (kt + 1) * 32); stageA(buf ^ 1, (kt + 1) * 32); }
        bf16x8 ah[FM], al[FM], bh[FN], bl[FN];
#pragma unroll
        for (int mi = 0; mi < FM; mi++) {
            const int r = wr * (FM * 16) + mi * 16 + li;
            const int fs = (r + (r >> 2)) & 3;
            ah[mi] = bc16(&sA[buf * AHALF + r * 32 + ((ks ^ fs)) * 8]);
            al[mi] = bc16(&sA[buf * AHALF + BM * 32 + r * 32 + ((ks ^ fs)) * 8]);
        }
#pragma unroll
        for (int ni = 0; ni < FN; ni++) {
            const int r = wc * (FN * 16) + ni * 16 + li;
            const int fs = (r + (r >> 2)) & 3;
            bh[ni] = bc16(&sB[buf * BHALF + r * 32 + ((ks ^ fs)) * 8]);
            bl[ni] = bc16(&sB[buf * BHALF + 4096 + r * 32 + ((ks ^ fs)) * 8]);
        }
#pragma unroll
        for (int mi = 0; mi < FM; mi++)
#pragma unroll
            for (int ni = 0; ni < FN; ni++) acc[mi][ni] = mfma16(ah[mi], bh[ni], acc[mi][ni]);
#pragma unroll
        for (int mi = 0; mi < FM; mi++)
#pragma unroll
            for (int ni = 0; ni < FN; ni++) acc[mi][ni] = mfma16(ah[mi], bl[ni], acc[mi][ni]);
#pragma unroll
        for (int mi = 0; mi < FM; mi++)
#pragma unroll
            for (int ni = 0; ni < FN; ni++) acc[mi][ni] = mfma16(al[mi], bh[ni], acc[mi][ni]);
        __syncthreads();
        buf ^= 1;
    }

    // ---- epilogue (C/D: col = lane&15, row = (lane>>4)*4 + reg)
#pragma unroll
    for (int mi = 0; mi < FM; mi++)
#pragma unroll
        for (int ni = 0; ni < FN; ni++) {
            const int n = n0 + wc * (FN * 16) + ni * 16 + (lane & 15);
            const int mb = m0 + wr * (FM * 16) + mi * 16 + (lane >> 4) * 4;
            unsigned short hx[4], lx[4];
#pragma unroll
            for (int r4 = 0; r4 < 4; r4++) {
                const int m = mb + r4;
                float v = acc[mi][ni][r4];
                if (bias) v += bias[n];
                if constexpr (GELU) v = 0.5f * v * (1.f + erff(v * 0.70710678118654752f));
                long id;
                if constexpr (IDX == 0)      id = (long)z * strC + (long)m * ldc + n;
                else                         id = ((long)(m >> 2)) * 16384
                                                + (long)((n >> 9) * 4 + (m & 3)) * 512 + (n & 511);
                if constexpr (OMODE == 1) {
                    unsigned short h, l; split2(v, h, l);
                    ((unsigned short*)Ch_)[id] = h;
                    ((unsigned short*)Cl_)[id] = l;
                    hx[r4] = h; lx[r4] = l;
                } else {
                    ((float*)Ch_)[id] = v;
                }
            }
            if constexpr (XTW) {
                // xT[b][c][s]: the 4 r4 values are 4 consecutive s at column n
                const int b = mb >> 9, s = mb & 511;
                const long o = (long)b * 262144 + (long)n * 512 + s;
                union { uint2 v; unsigned short u[4]; } ph, pl;
#pragma unroll
                for (int j = 0; j < 4; j++) { ph.u[j] = hx[j]; pl.u[j] = lx[j]; }
                *(uint2*)(xTh_ + o) = ph.v;
                *(uint2*)(xTl_ + o) = pl.v;
            }
        }
}

// ---------------------------------------------------------------------------
// Fused attention, 512 threads (8 waves) — round-9/10 proven, unchanged.
// ---------------------------------------------------------------------------
__global__ __launch_bounds__(512)
void fused_attn(const unsigned short* __restrict__ A_h, const unsigned short* __restrict__ A_l,
                const unsigned short* __restrict__ x_h, const unsigned short* __restrict__ x_l,
                const unsigned short* __restrict__ xT_h, const unsigned short* __restrict__ xT_l,
                unsigned short* __restrict__ U_h, unsigned short* __restrict__ U_l)
{
    __shared__ __align__(16) unsigned short sB[2][2][8192];
    __shared__ __align__(16) unsigned short sA[2][2][512];
    __shared__ __align__(16) unsigned short sP[2][16][16][32];
    __shared__ float redm[8][16], reds[8][16];

    const int tid = threadIdx.x;
    const int lin  = blockIdx.x + 2 * blockIdx.y;
    const int orig = (lin & 7) * 16 + (lin >> 3);
    const int b = orig >> 1, r0 = (orig & 1) * 16;
    const int lane = tid & 63, w = tid >> 6;
    const int li = lane & 15, ks = lane >> 4;
    const unsigned short* Ah = A_h + b * 16384 + r0 * 512;
    const unsigned short* Al = A_l + b * 16384 + r0 * 512;
    const unsigned short* xh = x_h + (long)b * 262144;
    const unsigned short* xl = x_l + (long)b * 262144;
    const unsigned short* xTh = xT_h + (long)b * 262144;
    const unsigned short* xTl = xT_l + (long)b * 262144;

    auto stage_B = [&](int buf, const unsigned short* sh, const unsigned short* sl2,
                       int row0, int k0) {
#pragma unroll
        for (int i = 0; i < 4; i++) {
            const int c2 = tid + 512 * i;
            const int p = c2 >> 10, cc = c2 & 1023, r = cc >> 2, sl = cc & 3;
            const int fs = (r + (r >> 2)) & 3;
            const unsigned short* g = (p ? sl2 : sh) + (long)(row0 + r) * 512 + k0 + (sl ^ fs) * 8;
            gload16(g, &sB[buf][p][r * 32 + sl * 8]);
        }
    };
    auto stage_A = [&](int buf, int k0) {
        if (tid < 128) {
            const int p = tid >> 6, c = tid & 63, r = c >> 2, sl = c & 3;
            const int fs = (r + (r >> 2)) & 3;
            const unsigned short* g = (p ? Al : Ah) + (long)r * 512 + k0 + (sl ^ fs) * 8;
            gload16(g, &sA[buf][p][r * 32 + sl * 8]);
        }
    };

    f32x4 acc[4];
#pragma unroll
    for (int i = 0; i < 4; i++) acc[i] = f32x4{0.f, 0.f, 0.f, 0.f};

    stage_B(0, xh, xl, 0, 0);
    stage_A(0, 0);
    __syncthreads();
    int buf = 0;
    const int fsa = (li + (li >> 2)) & 3;
    for (int t = 0; t < 32; t++) {
        const int half = t >> 4;
        const int nt = t + 1;
        if (nt < 32) {
            stage_B(buf ^ 1, xh, xl, (nt >> 4) * 256, (nt & 15) * 32);
            stage_A(buf ^ 1, (nt & 15) * 32);
        }
        bf16x8 ah = bc16(&sA[buf][0][li * 32 + ((ks ^ fsa)) * 8]);
        bf16x8 al = bc16(&sA[buf][1][li * 32 + ((ks ^ fsa)) * 8]);
        bf16x8 bh[2], bl[2];
#pragma unroll
        for (int ni = 0; ni < 2; ni++) {
            const int r = w * 32 + ni * 16 + li;
            const int fs = (r + (r >> 2)) & 3;
            bh[ni] = bc16(&sB[buf][0][r * 32 + ((ks ^ fs)) * 8]);
            bl[ni] = bc16(&sB[buf][1][r * 32 + ((ks ^ fs)) * 8]);
        }
#pragma unroll
        for (int ni = 0; ni < 2; ni++) acc[half * 2 + ni] = mfma16(ah, bh[ni], acc[half * 2 + ni]);
#pragma unroll
        for (int ni = 0; ni < 2; ni++) acc[half * 2 + ni] = mfma16(ah, bl[ni], acc[half * 2 + ni]);
#pragma unroll
        for (int ni = 0; ni < 2; ni++) acc[half * 2 + ni] = mfma16(al, bh[ni], acc[half * 2 + ni]);
        __syncthreads();
        buf ^= 1;
    }

    stage_B(buf, xTh, xTl, 0, 0);

    float M[4], S[4];
#pragma unroll
    for (int r4 = 0; r4 < 4; r4++) {
        float m = acc[0][r4];
#pragma unroll
        for (int i = 1; i < 4; i++) m = fmaxf(m, acc[i][r4]);
#pragma unroll
        for (int o = 1; o < 16; o <<= 1) m = fmaxf(m, __shfl_xor(m, o));
        M[r4] = m;
    }
    if (li == 0) {
#pragma unroll
        for (int r4 = 0; r4 < 4; r4++) redm[w][ks * 4 + r4] = M[r4];
    }
    __syncthreads();
#pragma unroll
    for (int r4 = 0; r4 < 4; r4++) {
        float m = redm[0][ks * 4 + r4];
#pragma unroll
        for (int ww = 1; ww < 8; ww++) m = fmaxf(m, redm[ww][ks * 4 + r4]);
        M[r4] = m;
    }
#pragma unroll
    for (int i = 0; i < 4; i++)
#pragma unroll
        for (int r4 = 0; r4 < 4; r4++) acc[i][r4] = expf(acc[i][r4] - M[r4]);
#pragma unroll
    for (int r4 = 0; r4 < 4; r4++) {
        float s = 0.f;
#pragma unroll
        for (int i = 0; i < 4; i++) s += acc[i][r4];
#pragma unroll
        for (int o = 1; o < 16; o <<= 1) s += __shfl_xor(s, o);
        S[r4] = s;
    }
    if (li == 0) {
#pragma unroll
        for (int r4 = 0; r4 < 4; r4++) reds[w][ks * 4 + r4] = S[r4];
    }
    __syncthreads();
#pragma unroll
    for (int r4 = 0; r4 < 4; r4++) {
        float s = 0.f;
#pragma unroll
        for (int ww = 0; ww < 8; ww++) s += reds[ww][ks * 4 + r4];
        S[r4] = 1.f / s;
    }
#pragma unroll
    for (int i = 0; i < 4; i++) {
        const int hf = i >> 1, ni = i & 1;
        const int s = hf * 256 + w * 32 + ni * 16 + li;
        const int kt = s >> 5, kks = (s >> 3) & 3, j = s & 7;
#pragma unroll
        for (int r4 = 0; r4 < 4; r4++) {
            const int row = ks * 4 + r4;
            const int fs = (row + (row >> 2)) & 3;
            unsigned short h, l2; split2(acc[i][r4] * S[r4], h, l2);
            sP[0][kt][row][(kks ^ fs) * 8 + j] = h;
            sP[1][kt][row][(kks ^ fs) * 8 + j] = l2;
        }
    }
    __syncthreads();

    f32x4 acc2[4];
#pragma unroll
    for (int i = 0; i < 4; i++) acc2[i] = f32x4{0.f, 0.f, 0.f, 0.f};
    for (int t = 0; t < 32; t++) {
        const int half = t >> 4, kt = t & 15;
        const int nt = t + 1;
        if (nt < 32) stage_B(buf ^ 1, xTh, xTl, (nt >> 4) * 256, (nt & 15) * 32);
        bf16x8 ph = bc16(&sP[0][kt][li][(ks ^ fsa) * 8]);
        bf16x8 pl = bc16(&sP[1][kt][li][(ks ^ fsa) * 8]);
        bf16x8 bh[2], bl[2];
#pragma unroll
        for (int ni = 0; ni < 2; ni++) {
            const int r = w * 32 + ni * 16 + li;
            const int fs = (r + (r >> 2)) & 3;
            bh[ni] = bc16(&sB[buf][0][r * 32 + ((ks ^ fs)) * 8]);
            bl[ni] = bc16(&sB[buf][1][r * 32 + ((ks ^ fs)) * 8]);
        }
#pragma unroll
        for (int ni = 0; ni < 2; ni++) acc2[half * 2 + ni] = mfma16(ph, bh[ni], acc2[half * 2 + ni]);
#pragma unroll
        for (int ni = 0; ni < 2; ni++) acc2[half * 2 + ni] = mfma16(ph, bl[ni], acc2[half * 2 + ni]);
#pragma unroll
        for (int ni = 0; ni < 2; ni++) acc2[half * 2 + ni] = mfma16(pl, bh[ni], acc2[half * 2 + ni]);
        __syncthreads();
        buf ^= 1;
    }

#pragma unroll
    for (int i = 0; i < 4; i++) {
        const int hf = i >> 1, ni = i & 1;
        const int n = hf * 256 + w * 32 + ni * 16 + li;
#pragma unroll
        for (int r4 = 0; r4 < 4; r4++) {
            const int m = r0 + ks * 4 + r4;
            const long id = ((long)b * 4 + (m & 3)) * 4096 + (long)(m >> 2) * 512 + n;
            unsigned short h, l2; split2(acc2[i][r4], h, l2);
            U_h[id] = h; U_l[id] = l2;
        }
    }
}

// ---------------------------------------------------------------------------
// Fused FFN (round-10 proven, unchanged): block (cx in [0,32), by row-block).
// ---------------------------------------------------------------------------
__global__ __launch_bounds__(256)
void ffn_fused(const unsigned short* __restrict__ q_h, const unsigned short* __restrict__ q_l,
               const unsigned short* __restrict__ W1T_h, const unsigned short* __restrict__ W1T_l,
               const float* __restrict__ b1,
               const unsigned short* __restrict__ W2T_h, const unsigned short* __restrict__ W2T_l,
               float* __restrict__ parts)
{
    __shared__ __align__(16) unsigned short sA[2 * 1024];
    __shared__ __align__(16) unsigned short sB[2 * 4096];
    __shared__ __align__(16) unsigned short sB2[8192];
    __shared__ __align__(16) unsigned short sF[2][2][16][32];
    const int cx = blockIdx.x, m0 = blockIdx.y * 16;
    const int tid = threadIdx.x, lane = tid & 63, w = tid >> 6;
    const int li = lane & 15, ks = lane >> 4;
    const int n0 = cx * 64;

    auto stageB1 = [&](int buf, int k0) {
#pragma unroll
        for (int i = 0; i < 2; i++) {
            const int c = tid + 256 * i;
            const int p = c >> 8, cc = c & 255, r = cc >> 2, sl = cc & 3;
            const int fs = (r + (r >> 2)) & 3;
            const unsigned short* g = (p ? W1T_l : W1T_h) + (long)(n0 + r) * 512 + k0 + (sl ^ fs) * 8;
            gload16(g, sB + buf * 4096 + p * 2048 + r * 32 + sl * 8);
        }
    };
    auto stageA1 = [&](int buf, int k0) {
        if (tid < 128) {
            const int p = tid >> 6, c = tid & 63, r = c >> 2, sl = c & 3;
            const int fs = (r + (r >> 2)) & 3;
            const unsigned short* g = (p ? q_l : q_h) + (long)(m0 + r) * 512 + k0 + (sl ^ fs) * 8;
            gload16(g, sA + buf * 1024 + p * 512 + r * 32 + sl * 8);
        }
    };

    f32x4 acc = f32x4{0.f, 0.f, 0.f, 0.f};
    int buf = 0;
    stageB1(0, 0); stageA1(0, 0);
    __syncthreads();
    const int fsa = (li + (li >> 2)) & 3;
    for (int kt = 0; kt < 16; kt++) {
        if (kt + 1 < 16) { stageB1(buf ^ 1, (kt + 1) * 32); stageA1(buf ^ 1, (kt + 1) * 32); }
        bf16x8 ah = bc16(sA + buf * 1024 + li * 32 + ((ks ^ fsa)) * 8);
        bf16x8 al = bc16(sA + buf * 1024 + 512 + li * 32 + ((ks ^ fsa)) * 8);
        const int r = w * 16 + li;
        const int fs = (r + (r >> 2)) & 3;
        bf16x8 bh = bc16(sB + buf * 4096 + r * 32 + ((ks ^ fs)) * 8);
        bf16x8 bl = bc16(sB + buf * 4096 + 2048 + r * 32 + ((ks ^ fs)) * 8);
        acc = mfma16(ah, bh, acc);
        acc = mfma16(ah, bl, acc);
        acc = mfma16(al, bh, acc);
        __syncthreads();
        buf ^= 1;
    }

#pragma unroll
    for (int r4 = 0; r4 < 4; r4++) {
        const int row = ks * 4 + r4;
        const int fs = (row + (row >> 2)) & 3;
        const int n = w * 16 + li;
        float v = acc[r4] + b1[n0 + n];
        v = 0.5f * v * (1.f + erff(v * 0.70710678118654752f));
        const int kt = n >> 5, kks = (n >> 3) & 3, j = n & 7;
        unsigned short h, l2; split2(v, h, l2);
        sF[0][kt][row][(kks ^ fs) * 8 + j] = h;
        sF[1][kt][row][(kks ^ fs) * 8 + j] = l2;
    }
    __syncthreads();

    for (int nc = 0; nc < 4; nc++) {
        f32x4 acc2[2];
#pragma unroll
        for (int j = 0; j < 2; j++) acc2[j] = f32x4{0.f, 0.f, 0.f, 0.f};
        for (int kt2 = 0; kt2 < 2; kt2++) {
            __syncthreads();
#pragma unroll
            for (int i = 0; i < 4; i++) {
                const int c = tid + 256 * i;
                const int p = c >> 9, cc = c & 511, r = cc >> 2, sl = cc & 3;
                const int fs = (r + (r >> 2)) & 3;
                const unsigned short* g = (p ? W2T_l : W2T_h)
                    + (long)(nc * 128 + r) * 2048 + cx * 64 + kt2 * 32 + (sl ^ fs) * 8;
                gload16(g, sB2 + p * 4096 + r * 32 + sl * 8);
            }
            __syncthreads();
            bf16x8 fh, fl, bh[2], bl[2];
            {
                const int row = li;
                const int fs = (row + (row >> 2)) & 3;
                fh = bc16(&sF[0][kt2][row][(ks ^ fs) * 8]);
                fl = bc16(&sF[1][kt2][row][(ks ^ fs) * 8]);
            }
#pragma unroll
            for (int ni = 0; ni < 2; ni++) {
                const int r = w * 32 + ni * 16 + li;
                const int fs = (r + (r >> 2)) & 3;
                bh[ni] = bc16(sB2 + r * 32 + (ks ^ fs) * 8);
                bl[ni] = bc16(sB2 + 4096 + r * 32 + (ks ^ fs) * 8);
            }
#pragma unroll
            for (int ni = 0; ni < 2; ni++) acc2[ni] = mfma16(fh, bh[ni], acc2[ni]);
#pragma unroll
            for (int ni = 0; ni < 2; ni++) acc2[ni] = mfma16(fh, bl[ni], acc2[ni]);
#pragma unroll
            for (int ni = 0; ni < 2; ni++) acc2[ni] = mfma16(fl, bh[ni], acc2[ni]);
        }
#pragma unroll
        for (int r4 = 0; r4 < 4; r4++) {
            const int m = m0 + ks * 4 + r4;
#pragma unroll
            for (int ni = 0; ni < 2; ni++) {
                const int n2 = nc * 128 + w * 32 + ni * 16 + li;
                parts[(long)cx * 131072 + (long)m * 512 + n2] = acc2[ni][r4];
            }
        }
    }
}

// ===========================================================================
// Prep bodies + prep kernels
// ===========================================================================

__device__ void prepT_body(float* t, int bx, int by, int z,
                           const float* __restrict__ in,
                           unsigned short* __restrict__ Th, unsigned short* __restrict__ Tl,
                           int ldin, int ldo, long inStride, long outStride)
{
    const int n0 = bx * 64, k0 = by * 64;
    const int tid = threadIdx.x;
    const float* src = in + (long)z * inStride;
#pragma unroll
    for (int i = 0; i < 4; i++) {
        int ch = tid + 256 * i;
        int r = ch >> 4, q = ch & 15;
        float4 v = *(const float4*)(src + (long)(k0 + r) * ldin + n0 + q * 4);
        t[r * 68 + q * 4 + 0] = v.x; t[r * 68 + q * 4 + 1] = v.y;
        t[r * 68 + q * 4 + 2] = v.z; t[r * 68 + q * 4 + 3] = v.w;
    }
    __syncthreads();
#pragma unroll
    for (int i = 0; i < 4; i++) {
        int ch = tid + 256 * i;
        int rc = ch >> 4, qk = ch & 15;
        union { uint2 v; unsigned short u[4]; } oh, ol;
#pragma unroll
        for (int j = 0; j < 4; j++) split2(t[(qk * 4 + j) * 68 + rc], oh.u[j], ol.u[j]);
        long o = (long)z * outStride + (long)(n0 + rc) * ldo + k0 + qk * 4;
        *(uint2*)(Th + o) = oh.v;
        *(uint2*)(Tl + o) = ol.v;
    }
}

__device__ void t32_body(float* t, int bx, int by, int z,
                         const float* __restrict__ in, float* __restrict__ out, long zstr)
{
    const int c0 = bx * 64, r0 = by * 64;
    const int tid = threadIdx.x;
#pragma unroll
    for (int i = 0; i < 4; i++) {
        int ch = tid + 256 * i;
        int r = ch >> 4, q = ch & 15;
        float4 v = *(const float4*)(in + (long)z * zstr + (long)(r0 + r) * 512 + c0 + q * 4);
        t[r * 65 + q * 4 + 0] = v.x; t[r * 65 + q * 4 + 1] = v.y;
        t[r * 65 + q * 4 + 2] = v.z; t[r * 65 + q * 4 + 3] = v.w;
    }
    __syncthreads();
#pragma unroll
    for (int i = 0; i < 4; i++) {
        int ch = tid + 256 * i;
        int rc = ch >> 4, qk = ch & 15;
        float4 o;
        o.x = t[(qk * 4 + 0) * 65 + rc]; o.y = t[(qk * 4 + 1) * 65 + rc];
        o.z = t[(qk * 4 + 2) * 65 + rc]; o.w = t[(qk * 4 + 3) * 65 + rc];
        *(float4*)(out + (long)z * zstr + (long)(c0 + rc) * 512 + r0 + qk * 4) = o;
    }
}

// pre_prep: mm split (4096 blocks) | pwT (128 blocks)  -> grid 4224
__global__ __launch_bounds__(256)
void pre_prep(const float* __restrict__ mm, unsigned short* __restrict__ mm_h,
              unsigned short* __restrict__ mm_l,
              const float* __restrict__ projW, unsigned short* __restrict__ pwT_h,
              unsigned short* __restrict__ pwT_l)
{
    __shared__ float t[64 * 68];
    const int bid = blockIdx.x;
    if (bid < 4096) {
        const long gt = (long)bid * 256 + threadIdx.x;
#pragma unroll
        for (int j = 0; j < 4; j++) {
            const long off = (gt + (long)j * 1048576) * 8;
            float4 v0 = *(const float4*)(mm + off);
            float4 v1 = *(const float4*)(mm + off + 4);
            float vv[8] = {v0.x, v0.y, v0.z, v0.w, v1.x, v1.y, v1.z, v1.w};
            union { s16x8 v; unsigned short u[8]; } hh, ll;
#pragma unroll
            for (int k = 0; k < 8; k++) split2(vv[k], hh.u[k], ll.u[k]);
            *(s16x8*)(mm_h + off) = hh.v;
            *(s16x8*)(mm_l + off) = ll.v;
        }
    } else {
        int u = bid - 4096;
        prepT_body(t, u & 7, u >> 3, 0, projW, pwT_h, pwT_l, 512, 1024, 0, 0);
    }
}

// post_prep: W1T (1024) | W2T (1024) | WoT (256)  -> grid 2304 (after proj!)
__global__ __launch_bounds__(256)
void post_prep(const float* W1, unsigned short* W1T_h, unsigned short* W1T_l,
               const float* W2, unsigned short* W2T_h, unsigned short* W2T_l,
               const float* Wo, float* WoT)
{
    __shared__ float t[64 * 68];
    const int bid = blockIdx.x;
    if (bid < 1024) {
        prepT_body(t, bid & 31, (bid >> 5) & 7, bid >> 8, W1, W1T_h, W1T_l, 2048, 512, 1048576, 1048576);
    } else if (bid < 2048) {
        int u = bid - 1024;
        prepT_body(t, u & 7, (u >> 3) & 31, u >> 8, W2, W2T_h, W2T_l, 512, 2048, 1048576, 1048576);
    } else {
        int u = bid - 2048;
        t32_body(t, u & 7, (u >> 3) & 7, u >> 6, Wo, WoT, 262144);
    }
}

__device__ void w2_body(unsigned short* sA, unsigned short* sB, int bx, int by, int z,
                        const float* A_, const float* B_, float scale,
                        unsigned short* Th, unsigned short* Tl,
                        long zsA, long zsB, long S1, long S2, long SMs)
{
    const int tid = threadIdx.x;
    const int m0 = by * 128, n0 = bx * 128;
    const int lane = tid & 63, w = tid >> 6, wr = w >> 1, wc = w & 1;
    const float* Ab = A_ + (long)(z >> 3) * zsA + (z & 7) * 64;
    const float* Bb = B_ + (long)(z >> 3) * zsB + (z & 7) * 64;

    f32x4 acc[4][4];
#pragma unroll
    for (int i = 0; i < 4; i++)
#pragma unroll
        for (int j = 0; j < 4; j++) acc[i][j] = f32x4{0.f, 0.f, 0.f, 0.f};

    for (int k0 = 0; k0 < 64; k0 += 32) {
        __syncthreads();
#pragma unroll
        for (int op = 0; op < 2; op++) {
            const float* src0 = op ? Bb : Ab;
            unsigned short* dst = op ? sB : sA;
#pragma unroll
            for (int i = 0; i < 2; i++) {
                const int c = tid + 256 * i;
                const int r = c >> 2, s = c & 3;
                const int fs = (r + (r >> 2)) & 3;
                const float* src = src0 + (long)((op ? n0 : m0) + r) * 512 + k0 + s * 8;
                float4 v0 = *(const float4*)src;
                float4 v1 = *(const float4*)(src + 4);
                float vv[8] = {v0.x, v0.y, v0.z, v0.w, v1.x, v1.y, v1.z, v1.w};
                union { s16x8 v; unsigned short u[8]; } hh, ll;
#pragma unroll
                for (int j = 0; j < 8; j++) split2(vv[j], hh.u[j], ll.u[j]);
                *(s16x8*)&dst[0 * 4096 + r * 32 + (s ^ fs) * 8] = hh.v;
                *(s16x8*)&dst[1 * 4096 + r * 32 + (s ^ fs) * 8] = ll.v;
            }
        }
        __syncthreads();
        const int li = lane & 15, ks = lane >> 4;
        bf16x8 ah[4], al[4], bh[4], bl[4];
#pragma unroll
        for (int mi = 0; mi < 4; mi++) {
            const int r = wr * 64 + mi * 16 + li;
            const int fs = (r + (r >> 2)) & 3;
            ah[mi] = bc16(sA + r * 32 + (ks ^ fs) * 8);
            al[mi] = bc16(sA + 4096 + r * 32 + (ks ^ fs) * 8);
        }
#pragma unroll
        for (int ni = 0; ni < 4; ni++) {
            const int r = wc * 64 + ni * 16 + li;
            const int fs = (r + (r >> 2)) & 3;
            bh[ni] = bc16(sB + r * 32 + (ks ^ fs) * 8);
            bl[ni] = bc16(sB + 4096 + r * 32 + (ks ^ fs) * 8);
        }
#pragma unroll
        for (int mi = 0; mi < 4; mi++)
#pragma unroll
            for (int ni = 0; ni < 4; ni++) acc[mi][ni] = mfma16(ah[mi], bh[ni], acc[mi][ni]);
#pragma unroll
        for (int mi = 0; mi < 4; mi++)
#pragma unroll
            for (int ni = 0; ni < 4; ni++) acc[mi][ni] = mfma16(ah[mi], bl[ni], acc[mi][ni]);
#pragma unroll
        for (int mi = 0; mi < 4; mi++)
#pragma unroll
            for (int ni = 0; ni < 4; ni++) acc[mi][ni] = mfma16(al[mi], bh[ni], acc[mi][ni]);
    }
#pragma unroll
    for (int mi = 0; mi < 4; mi++)
#pragma unroll
        for (int r4 = 0; r4 < 4; r4++) {
            const int m = m0 + wr * 64 + mi * 16 + (lane >> 4) * 4 + r4;
#pragma unroll
            for (int ni = 0; ni < 4; ni++) {
                const int n = n0 + wc * 64 + ni * 16 + (lane & 15);
                float v = acc[mi][ni][r4] * scale;
                unsigned short h, l; split2(v, h, l);
                long id = (long)(z >> 3) * S1 + (long)(z & 7) * S2 + (long)m * SMs + n;
                Th[id] = h; Tl[id] = l;
            }
        }
}

__global__ __launch_bounds__(256)
void w2_merged(const float* Wk, const float* Wq,
               unsigned short* MT_h, unsigned short* MT_l,
               const float* WoT, const float* Wv,
               unsigned short* WVOT_h, unsigned short* WVOT_l)
{
    __shared__ __align__(16) unsigned short sA[2 * 4096];
    __shared__ __align__(16) unsigned short sB[2 * 4096];
    const int bid = blockIdx.x;
    if (bid < 512) {
        w2_body(sA, sB, bid & 3, (bid >> 2) & 3, bid >> 4, Wk, Wq, 0.125f, MT_h, MT_l,
                262144, 262144, 2097152, 262144, 512);
    } else {
        int u = bid - 512;
        w2_body(sA, sB, u & 3, (u >> 2) & 3, u >> 4, WoT, Wv, 1.f, WVOT_h, WVOT_l,
                262144, 262144, 2097152, 512, 4096);
    }
}

__global__ __launch_bounds__(256)
void small_prep(const float* cbook, float* cbT, float* cn,
                const float* bq, const float* Wk, float* biasA,
                const float* bv, const float* Wo, const float* bo, float* biasO,
                const float* qt, float* q, unsigned short* qh_s, unsigned short* ql_s)
{
    __shared__ float sm[256];
    const int bid = blockIdx.x, tid = threadIdx.x;
    if (bid < 768) {
        const int rowi = bid, l = rowi >> 8, j = rowi & 255;
        const float* row = cbook + (long)rowi * 512;
        float v0 = row[tid], v1 = row[tid + 256];
        cbT[(long)l * 131072 + (long)tid * 256 + j]         = v0;
        cbT[(long)l * 131072 + (long)(tid + 256) * 256 + j] = v1;
        float s = v0 * v0 + v1 * v1;
#pragma unroll
        for (int o = 32; o > 0; o >>= 1) s += __shfl_xor(s, o);
        if ((tid & 63) == 0) sm[tid >> 6] = s;
        __syncthreads();
        if (tid == 0) cn[rowi] = sm[0] + sm[1] + sm[2] + sm[3];
    } else if (bid < 832) {
        const int gid = (bid - 768) * 256 + tid;
        const int l = gid >> 12, hc = gid & 4095, h = hc >> 9, c = hc & 511;
        const float* b = bq + l * 512 + h * 64;
        const float* w = Wk + (long)l * 262144 + (long)c * 512 + h * 64;
        float s = 0.f;
#pragma unroll 16
        for (int d = 0; d < 64; d++) s = fmaf(b[d], w[d], s);
        biasA[gid] = 0.125f * s;
    } else if (bid < 864) {
        const int u = bid - 832;
        const int l = u >> 3, oc = u & 7;
        const int o = oc * 64 + (tid & 63), j4 = tid >> 6;
        float acc = 0.f;
        for (int j = j4; j < 512; j += 4)
            acc = fmaf(bv[l * 512 + j], Wo[(long)l * 262144 + (long)j * 512 + o], acc);
        sm[j4 * 64 + (tid & 63)] = acc;
        __syncthreads();
        if (tid < 64) {
            float s = sm[tid] + sm[64 + tid] + sm[128 + tid] + sm[192 + tid]
                    + bo[l * 512 + oc * 64 + tid];
            biasO[l * 512 + oc * 64 + tid] = s;
        }
    } else {
        const int r = bid - 864, t = r & 3;
        const long base = (long)r * 512;
        float a = qt[t * 512 + tid], c = qt[t * 512 + 256 + tid];
        q[base + tid] = a; q[base + 256 + tid] = c;
        unsigned short h, l;
        split2(a, h, l); qh_s[base + tid] = h;       ql_s[base + tid] = l;
        split2(c, h, l); qh_s[base + tid + 256] = h; ql_s[base + tid + 256] = l;
    }
}

// ---- q = LayerNorm(q + sum_z parts[z] + bias)*g + b; emit split q ----------
__global__ __launch_bounds__(256) void add_ln_sum(float* __restrict__ q,
                                                  const float* __restrict__ parts, int np,
                                                  const float* __restrict__ bias,
                                                  const float* __restrict__ g,
                                                  const float* __restrict__ b,
                                                  unsigned short* __restrict__ qh_s,
                                                  unsigned short* __restrict__ ql_s)
{
    __shared__ float red[4];
    const int tid = threadIdx.x;
    const long base = (long)blockIdx.x * 512;
    float* row = q + base;
    float v0 = row[tid] + bias[tid];
    float v1 = row[tid + 256] + bias[tid + 256];
    for (int z = 0; z < np; z++) {
        v0 += parts[(long)z * 131072 + base + tid];
        v1 += parts[(long)z * 131072 + base + tid + 256];
    }
    float s = v0 + v1;
#pragma unroll
    for (int o = 32; o > 0; o >>= 1) s += __shfl_xor(s, o);
    if ((tid & 63) == 0) red[tid >> 6] = s;
    __syncthreads();
    float mu = (red[0] + red[1] + red[2] + red[3]) * (1.f / 512.f);
    __syncthreads();
    float c0 = v0 - mu, c1 = v1 - mu;
    float sq = c0 * c0 + c1 * c1;
#pragma unroll
    for (int o = 32; o > 0; o >>= 1) sq += __shfl_xor(sq, o);
    if ((tid & 63) == 0) red[tid >> 6] = sq;
    __syncthreads();
    float var = (red[0] + red[1] + red[2] + red[3]) * (1.f / 512.f);
    float rs = rsqrtf(var + 1e-5f);
    float o0 = c0 * rs * g[tid] + b[tid];
    float o1 = c1 * rs * g[tid + 256] + b[tid + 256];
    row[tid] = o0; row[tid + 256] = o1;
    unsigned short h, l;
    split2(o0, h, l); qh_s[base + tid] = h;       ql_s[base + tid] = l;
    split2(o1, h, l); qh_s[base + tid + 256] = h; ql_s[base + tid + 256] = l;
}

__global__ __launch_bounds__(256) void rq_kernel(const float* __restrict__ qf,
                                                 const float* __restrict__ cb,
                                                 const float* __restrict__ cbT,
                                                 const float* __restrict__ cn,
                                                 float* __restrict__ out)
{
    __shared__ float r[512], rec[512];
    __shared__ float rd[4]; __shared__ int ri[4];
    __shared__ int sids[3];
    const int p = blockIdx.x, tid = threadIdx.x;
    r[tid]         = qf[(long)p * 512 + tid];
    r[tid + 256]   = qf[(long)p * 512 + 256 + tid];
    rec[tid] = 0.f; rec[tid + 256] = 0.f;
    __syncthreads();
    for (int l = 0; l < 3; l++) {
        const float* ct = cbT + (long)l * 131072;
        float dot = 0.f;
#pragma unroll 8
        for (int k = 0; k < 512; k++) dot = fmaf(r[k], ct[(long)k * 256 + tid], dot);
        float d2 = cn[l * 256 + tid] - 2.f * dot;
        int idx = tid;
#pragma unroll
        for (int o = 32; o > 0; o >>= 1) {
            float od = __shfl_xor(d2, o); int oi = __shfl_xor(idx, o);
            if (od < d2 || (od == d2 && oi < idx)) { d2 = od; idx = oi; }
        }
        if ((tid & 63) == 0) { rd[tid >> 6] = d2; ri[tid >> 6] = idx; }
        __syncthreads();
        if (tid == 0) {
            float bd = rd[0]; int bb = ri[0];
            for (int w = 1; w < 4; w++)
                if (rd[w] < bd || (rd[w] == bd && ri[w] < bb)) { bd = rd[w]; bb = ri[w]; }
            sids[l] = bb;
        }
        __syncthreads();
        const float* crow = cb + ((long)l * 256 + sids[l]) * 512;
        float c0 = crow[tid], c1 = crow[tid + 256];
        r[tid] -= c0; rec[tid] += c0;
        r[tid + 256] -= c1; rec[tid + 256] += c1;
        __syncthreads();
    }
    float* orec = out + 768 + (long)p * 512;
    orec[tid] = rec[tid]; orec[tid + 256] = rec[tid + 256];
    if (tid < 3) out[p * 3 + tid] = (float)sids[tid];
}

// ---------------------------------------------------------------------------
extern "C" void kernel_launch(void* const* d_in, const int* in_sizes, int n_in,
                              void* d_out, int out_size, void* d_ws, size_t ws_size,
                              hipStream_t stream)
{
    const float* mm    = (const float*)d_in[0];
    const float* projW = (const float*)d_in[1];
    const float* projb = (const float*)d_in[2];
    const float* qt    = (const float*)d_in[3];
    const float* Wq    = (const float*)d_in[4];
    const float* bq    = (const float*)d_in[5];
    const float* Wk    = (const float*)d_in[6];
    const float* Wv    = (const float*)d_in[8];
    const float* bv    = (const float*)d_in[9];
    const float* Wo    = (const float*)d_in[10];
    const float* bo    = (const float*)d_in[11];
    const float* W1    = (const float*)d_in[12];
    const float* b1    = (const float*)d_in[13];
    const float* W2    = (const float*)d_in[14];
    const float* b2    = (const float*)d_in[15];
    const float* lng   = (const float*)d_in[16];
    const float* lnb   = (const float*)d_in[17];
    const float* cbook = (const float*)d_in[18];

    char* p = (char*)d_ws;
    auto alloc = [&](size_t bytes) { char* r = p; p += (bytes + 255) & ~(size_t)255; return r; };

    // region X: mm split (128 MB), reused after proj for folded weights (100 MB)
    char* X = alloc(134217728ull);
    unsigned short* mm_h  = (unsigned short*)X;
    unsigned short* mm_l  = (unsigned short*)(X + 67108864);
    float*          WoT   = (float*)X;
    unsigned short* W1T_h = (unsigned short*)(X + 4194304);
    unsigned short* W1T_l = (unsigned short*)(X + 12582912);
    unsigned short* W2T_h = (unsigned short*)(X + 20971520);
    unsigned short* W2T_l = (unsigned short*)(X + 29360128);
    unsigned short* MT_h  = (unsigned short*)(X + 37748736);
    unsigned short* MT_l  = (unsigned short*)(X + 54525952);
    unsigned short* WVOT_h= (unsigned short*)(X + 71303168);
    unsigned short* WVOT_l= (unsigned short*)(X + 88080384);

    unsigned short* x_h   = (unsigned short*)alloc(16777216ull * 2);
    unsigned short* x_l   = (unsigned short*)alloc(16777216ull * 2);
    unsigned short* xT_h  = (unsigned short*)alloc(16777216ull * 2);
    unsigned short* xT_l  = (unsigned short*)alloc(16777216ull * 2);
    unsigned short* pwT_h = (unsigned short*)alloc(524288ull * 2);
    unsigned short* pwT_l = (unsigned short*)alloc(524288ull * 2);
    unsigned short* A_h   = (unsigned short*)alloc(1048576ull * 2);
    unsigned short* A_l   = (unsigned short*)alloc(1048576ull * 2);
    unsigned short* U_h   = (unsigned short*)alloc(1048576ull * 2);
    unsigned short* U_l   = (unsigned short*)alloc(1048576ull * 2);
    unsigned short* q_h   = (unsigned short*)alloc(131072ull * 2);
    unsigned short* q_l   = (unsigned short*)alloc(131072ull * 2);
    float* parts = (float*)alloc(32ull * 131072 * 4);
    float* q     = (float*)alloc(131072ull * 4);
    float* cbT   = (float*)alloc(393216ull * 4);
    float* cn    = (float*)alloc(768ull * 4);
    float* biasA = (float*)alloc(16384ull * 4);
    float* biasO = (float*)alloc(2048ull * 4);

    // 1. mm split + pwT prep
    pre_prep<<<4224, 256, 0, stream>>>(mm, mm_h, mm_l, projW, pwT_h, pwT_l);
    // 2. x = mm @ projW + projb (split out + direct xT writes)
    mfma_gemm<128, 4, 4, 2, 2, 0, 1, 0, false, true, true><<<dim3(4, 256, 1), 256, 0, stream>>>(
        mm_h, mm_l, pwT_h, pwT_l, projb, x_h, x_l, 1024, 1024, 1024, 512, 0, 0, 0, xT_h, xT_l);
    // 3. remaining preps (write over the mm region — proj already consumed it)
    post_prep<<<2304, 256, 0, stream>>>(W1, W1T_h, W1T_l, W2, W2T_h, W2T_l, Wo, WoT);
    w2_merged<<<1024, 256, 0, stream>>>(Wk, Wq, MT_h, MT_l, WoT, Wv, WVOT_h, WVOT_l);
    small_prep<<<1120, 256, 0, stream>>>(cbook, cbT, cn, bq, Wk, biasA,
                                         bv, Wo, bo, biasO, qt, q, q_h, q_l);

    for (int i = 0; i < 4; i++) {
        const unsigned short* MTh = MT_h + (long)i * 2097152;
        const unsigned short* MTl = MT_l + (long)i * 2097152;
        const unsigned short* WVh = WVOT_h + (long)i * 2097152;
        const unsigned short* WVl = WVOT_l + (long)i * 2097152;
        const unsigned short* W1h = W1T_h + (long)i * 1048576;
        const unsigned short* W1l = W1T_l + (long)i * 1048576;
        const unsigned short* W2h = W2T_h + (long)i * 1048576;
        const unsigned short* W2l = W2T_l + (long)i * 1048576;
        const float* b1i = b1 + i * 2048; const float* b2i = b2 + i * 512;
        const float* gi  = lng + i * 512; const float* bi_ = lnb + i * 512;

        // A[b][ht][c] = q @ MT + biasA   (BM=16: 512 blocks)
        mfma_gemm<16, 1, 2, 1, 4, 0, 1, 1, false, false, false><<<dim3(32, 16, 1), 256, 0, stream>>>(
            q_h, q_l, MTh, MTl, biasA + i * 4096, A_h, A_l, 512, 512, 512, 512, 0, 0, 0,
            nullptr, nullptr);
        // fused scores -> softmax -> U
        fused_attn<<<dim3(2, 64), 512, 0, stream>>>(A_h, A_l, x_h, x_l, xT_h, xT_l, U_h, U_l);
        // attn_out partials = U @ WVOT  (BM=16, split-K 8: 512 blocks)
        mfma_gemm<16, 1, 2, 1, 4, 0, 0, 0, false, false, false><<<dim3(4, 16, 8), 256, 0, stream>>>(
            U_h, U_l, WVh, WVl, nullptr, parts, nullptr, 512, 4096, 4096, 512,
            512, 512, 131072, nullptr, nullptr);
        add_ln_sum<<<256, 256, 0, stream>>>(q, parts, 8, biasO + i * 512, gi, bi_, q_h, q_l);
        // fused ffn1+ffn2 -> 32 partials (512 blocks)
        ffn_fused<<<dim3(32, 16), 256, 0, stream>>>(q_h, q_l, W1h, W1l, b1i, W2h, W2l, parts);
        add_ln_sum<<<256, 256, 0, stream>>>(q, parts, 32, b2i, gi, bi_, q_h, q_l);
    }

    rq_kernel<<<256, 256, 0, stream>>>(q, cbook, cbT, cn, (float*)d_out);
}

// Round 12
// 885.638 us; speedup vs baseline: 1.0233x; 1.0233x over previous
//
#include <hip/hip_runtime.h>
#include <math.h>

// ---------------------------------------------------------------------------
// OneRecTokenizer. B=64 S=512 MM=1024 HID=512 T=4 NL=4 NHEAD=8 DH=64 RQ_L=3 CB=256
// Round 12: round-10 base (871us proven) + xT written directly from proj
// epilogue (XTW, proven in r11) -> transpose_x eliminated. r11's mm pre-split
// reverted (proved neutral for proj, cost +35us).
// bf16x2 3-pass split everywhere: A*B ~= Ah*Bh + Ah*Bl + Al*Bh (rel err ~2^-17).
// ---------------------------------------------------------------------------

typedef __attribute__((ext_vector_type(8))) short   s16x8;
typedef __attribute__((ext_vector_type(8))) __bf16  bf16x8;
typedef __attribute__((ext_vector_type(4))) float   f32x4;

__device__ __forceinline__ void split2(float v, unsigned short& hi, unsigned short& lo) {
    unsigned u = __builtin_bit_cast(unsigned, v);
    hi = (unsigned short)(u >> 16);
    float hf = __builtin_bit_cast(float, u & 0xffff0000u);
    float l = v - hf;
    unsigned ul = __builtin_bit_cast(unsigned, l);
    lo = (unsigned short)((ul + 0x7fffu + ((ul >> 16) & 1u)) >> 16);
}

__device__ __forceinline__ f32x4 mfma16(bf16x8 a, bf16x8 b, f32x4 c) {
    return __builtin_amdgcn_mfma_f32_16x16x32_bf16(a, b, c, 0, 0, 0);
}

__device__ __forceinline__ void gload16(const void* g, void* l) {
    __builtin_amdgcn_global_load_lds(
        (const __attribute__((address_space(1))) unsigned*)g,
        (__attribute__((address_space(3))) unsigned*)l, 16, 0, 0);
}

__device__ __forceinline__ bf16x8 bc16(const unsigned short* p) {
    return __builtin_bit_cast(bf16x8, *(const s16x8*)p);
}

// ---------------------------------------------------------------------------
// Unified bf16x2 3-pass MFMA GEMM. BN=128.
// AMODE 0: A split bf16 (BM 16/32, gload_lds). AMODE 1: A fp32 split on the
// fly (BM=128, proj; ds_write staging). OMODE 0 fp32 / 1 split-bf16.
// IDX 0 plain, 1 A-scatter. XTW: also write xT[b][c][s] from accumulators.
// ---------------------------------------------------------------------------
template<int BM, int FM, int FN, int WR, int WC, int AMODE, int OMODE,
         int IDX, bool GELU, bool SWZ, bool XTW>
__global__ __launch_bounds__(256)
void mfma_gemm(const void* __restrict__ Ah_, const void* __restrict__ Al_,
               const unsigned short* __restrict__ Bh_, const unsigned short* __restrict__ Bl_,
               const float* __restrict__ bias,
               void* __restrict__ Ch_, void* __restrict__ Cl_,
               int K, int lda, int ldb, int ldc,
               long strA, long strB, long strC,
               unsigned short* __restrict__ xTh_, unsigned short* __restrict__ xTl_)
{
    constexpr int BHALF = 8192;
    constexpr int AHALF = 2 * BM * 32;
    __shared__ __align__(16) unsigned short sA[2 * AHALF];
    __shared__ __align__(16) unsigned short sB[2 * BHALF];

    int bx = blockIdx.x, by = blockIdx.y;
    if constexpr (SWZ) {
        int nb = gridDim.x * gridDim.y;
        int h  = bx + gridDim.x * by;
        int orig = (h & 7) * (nb >> 3) + (h >> 3);
        bx = orig % gridDim.x; by = orig / gridDim.x;
    }
    const int tid = threadIdx.x, z = blockIdx.z;
    const int m0 = by * BM, n0 = bx * 128;
    const int lane = tid & 63, w = tid >> 6;
    const int wr = w / WC, wc = w % WC;

    const float* Af = nullptr;
    const unsigned short *Ah = nullptr, *Al = nullptr;
    if constexpr (AMODE == 1) {
        Af = (const float*)Ah_;
    } else {
        Ah = (const unsigned short*)Ah_ + (long)z * strA;
        Al = (const unsigned short*)Al_ + (long)z * strA;
    }
    const unsigned short* Bh = Bh_ + (long)z * strB;
    const unsigned short* Bl = Bl_ + (long)z * strB;

    auto stageB = [&](int buf, int k0) {
#pragma unroll
        for (int i = 0; i < 4; i++) {
            const int c = tid + 256 * i;
            const int p = c >> 9, cc = c & 511, r = cc >> 2, sl = cc & 3;
            const int fs = (r + (r >> 2)) & 3;
            const unsigned short* g = (p ? Bl : Bh) + (long)(n0 + r) * ldb + k0 + ((sl ^ fs)) * 8;
            gload16(g, sB + buf * BHALF + p * 4096 + r * 32 + sl * 8);
        }
    };
    auto stageA = [&](int buf, int k0) {
        if constexpr (AMODE == 0 && BM == 32) {
            const int p = tid >> 7, c = tid & 127, r = c >> 2, sl = c & 3;
            const int fs = (r + (r >> 2)) & 3;
            const unsigned short* g = (p ? Al : Ah) + (long)(m0 + r) * lda + k0 + ((sl ^ fs)) * 8;
            gload16(g, sA + buf * AHALF + p * (BM * 32) + r * 32 + sl * 8);
        } else if constexpr (AMODE == 0 && BM == 16) {
            if (tid < 128) {
                const int p = tid >> 6, c = tid & 63, r = c >> 2, sl = c & 3;
                const int fs = (r + (r >> 2)) & 3;
                const unsigned short* g = (p ? Al : Ah) + (long)(m0 + r) * lda + k0 + ((sl ^ fs)) * 8;
                gload16(g, sA + buf * AHALF + p * (BM * 32) + r * 32 + sl * 8);
            }
        } else {  // AMODE == 1, BM == 128: fp32 split on the fly
            const int r = tid >> 1, hh2 = tid & 1;
            const int fs = (r + (r >> 2)) & 3;
            const float* src = Af + (long)(m0 + r) * lda + k0 + hh2 * 16;
#pragma unroll
            for (int s2 = 0; s2 < 2; s2++) {
                const int s = 2 * hh2 + s2;
                float4 v0 = *(const float4*)(src + s2 * 8);
                float4 v1 = *(const float4*)(src + s2 * 8 + 4);
                float vv[8] = {v0.x, v0.y, v0.z, v0.w, v1.x, v1.y, v1.z, v1.w};
                union { s16x8 v; unsigned short u[8]; } hu, lu;
#pragma unroll
                for (int j = 0; j < 8; j++) split2(vv[j], hu.u[j], lu.u[j]);
                *(s16x8*)&sA[buf * AHALF + r * 32 + ((s ^ fs)) * 8] = hu.v;
                *(s16x8*)&sA[buf * AHALF + BM * 32 + r * 32 + ((s ^ fs)) * 8] = lu.v;
            }
        }
    };

    f32x4 acc[FM][FN];
#pragma unroll
    for (int i = 0; i < FM; i++)
#pragma unroll
        for (int j = 0; j < FN; j++) acc[i][j] = f32x4{0.f, 0.f, 0.f, 0.f};

    const int NT = K / 32;
    int buf = 0;
    stageB(0, 0);
    stageA(0, 0);
    __syncthreads();

    const int li = lane & 15, ks = lane >> 4;

    for (int kt = 0; kt < NT; kt++) {
        if (kt + 1 < NT) { stageB(buf ^ 1, (kt + 1) * 32); stageA(buf ^ 1, (kt + 1) * 32); }
        bf16x8 ah[FM], al[FM], bh[FN], bl[FN];
#pragma unroll
        for (int mi = 0; mi < FM; mi++) {
            const int r = wr * (FM * 16) + mi * 16 + li;
            const int fs = (r + (r >> 2)) & 3;
            ah[mi] = bc16(&sA[buf * AHALF + r * 32 + ((ks ^ fs)) * 8]);
            al[mi] = bc16(&sA[buf * AHALF + BM * 32 + r * 32 + ((ks ^ fs)) * 8]);
        }
#pragma unroll
        for (int ni = 0; ni < FN; ni++) {
            const int r = wc * (FN * 16) + ni * 16 + li;
            const int fs = (r + (r >> 2)) & 3;
            bh[ni] = bc16(&sB[buf * BHALF + r * 32 + ((ks ^ fs)) * 8]);
            bl[ni] = bc16(&sB[buf * BHALF + 4096 + r * 32 + ((ks ^ fs)) * 8]);
        }
#pragma unroll
        for (int mi = 0; mi < FM; mi++)
#pragma unroll
            for (int ni = 0; ni < FN; ni++) acc[mi][ni] = mfma16(ah[mi], bh[ni], acc[mi][ni]);
#pragma unroll
        for (int mi = 0; mi < FM; mi++)
#pragma unroll
            for (int ni = 0; ni < FN; ni++) acc[mi][ni] = mfma16(ah[mi], bl[ni], acc[mi][ni]);
#pragma unroll
        for (int mi = 0; mi < FM; mi++)
#pragma unroll
            for (int ni = 0; ni < FN; ni++) acc[mi][ni] = mfma16(al[mi], bh[ni], acc[mi][ni]);
        __syncthreads();
        buf ^= 1;
    }

    // ---- epilogue (C/D: col = lane&15, row = (lane>>4)*4 + reg)
#pragma unroll
    for (int mi = 0; mi < FM; mi++)
#pragma unroll
        for (int ni = 0; ni < FN; ni++) {
            const int n = n0 + wc * (FN * 16) + ni * 16 + (lane & 15);
            const int mb = m0 + wr * (FM * 16) + mi * 16 + (lane >> 4) * 4;
            unsigned short hx[4], lx[4];
#pragma unroll
            for (int r4 = 0; r4 < 4; r4++) {
                const int m = mb + r4;
                float v = acc[mi][ni][r4];
                if (bias) v += bias[n];
                if constexpr (GELU) v = 0.5f * v * (1.f + erff(v * 0.70710678118654752f));
                long id;
                if constexpr (IDX == 0)      id = (long)z * strC + (long)m * ldc + n;
                else                         id = ((long)(m >> 2)) * 16384
                                                + (long)((n >> 9) * 4 + (m & 3)) * 512 + (n & 511);
                if constexpr (OMODE == 1) {
                    unsigned short h, l; split2(v, h, l);
                    ((unsigned short*)Ch_)[id] = h;
                    ((unsigned short*)Cl_)[id] = l;
                    hx[r4] = h; lx[r4] = l;
                } else {
                    ((float*)Ch_)[id] = v;
                }
            }
            if constexpr (XTW) {
                // xT[b][c][s]: the 4 r4 values are 4 consecutive s at column n
                const int b = mb >> 9, s = mb & 511;
                const long o = (long)b * 262144 + (long)n * 512 + s;
                union { uint2 v; unsigned short u[4]; } ph, pl;
#pragma unroll
                for (int j = 0; j < 4; j++) { ph.u[j] = hx[j]; pl.u[j] = lx[j]; }
                *(uint2*)(xTh_ + o) = ph.v;
                *(uint2*)(xTl_ + o) = pl.v;
            }
        }
}

// ---------------------------------------------------------------------------
// Fused attention, 512 threads (8 waves) — round-9/10 proven, unchanged.
// ---------------------------------------------------------------------------
__global__ __launch_bounds__(512)
void fused_attn(const unsigned short* __restrict__ A_h, const unsigned short* __restrict__ A_l,
                const unsigned short* __restrict__ x_h, const unsigned short* __restrict__ x_l,
                const unsigned short* __restrict__ xT_h, const unsigned short* __restrict__ xT_l,
                unsigned short* __restrict__ U_h, unsigned short* __restrict__ U_l)
{
    __shared__ __align__(16) unsigned short sB[2][2][8192];
    __shared__ __align__(16) unsigned short sA[2][2][512];
    __shared__ __align__(16) unsigned short sP[2][16][16][32];
    __shared__ float redm[8][16], reds[8][16];

    const int tid = threadIdx.x;
    const int lin  = blockIdx.x + 2 * blockIdx.y;
    const int orig = (lin & 7) * 16 + (lin >> 3);
    const int b = orig >> 1, r0 = (orig & 1) * 16;
    const int lane = tid & 63, w = tid >> 6;
    const int li = lane & 15, ks = lane >> 4;
    const unsigned short* Ah = A_h + b * 16384 + r0 * 512;
    const unsigned short* Al = A_l + b * 16384 + r0 * 512;
    const unsigned short* xh = x_h + (long)b * 262144;
    const unsigned short* xl = x_l + (long)b * 262144;
    const unsigned short* xTh = xT_h + (long)b * 262144;
    const unsigned short* xTl = xT_l + (long)b * 262144;

    auto stage_B = [&](int buf, const unsigned short* sh, const unsigned short* sl2,
                       int row0, int k0) {
#pragma unroll
        for (int i = 0; i < 4; i++) {
            const int c2 = tid + 512 * i;
            const int p = c2 >> 10, cc = c2 & 1023, r = cc >> 2, sl = cc & 3;
            const int fs = (r + (r >> 2)) & 3;
            const unsigned short* g = (p ? sl2 : sh) + (long)(row0 + r) * 512 + k0 + (sl ^ fs) * 8;
            gload16(g, &sB[buf][p][r * 32 + sl * 8]);
        }
    };
    auto stage_A = [&](int buf, int k0) {
        if (tid < 128) {
            const int p = tid >> 6, c = tid & 63, r = c >> 2, sl = c & 3;
            const int fs = (r + (r >> 2)) & 3;
            const unsigned short* g = (p ? Al : Ah) + (long)r * 512 + k0 + (sl ^ fs) * 8;
            gload16(g, &sA[buf][p][r * 32 + sl * 8]);
        }
    };

    f32x4 acc[4];
#pragma unroll
    for (int i = 0; i < 4; i++) acc[i] = f32x4{0.f, 0.f, 0.f, 0.f};

    stage_B(0, xh, xl, 0, 0);
    stage_A(0, 0);
    __syncthreads();
    int buf = 0;
    const int fsa = (li + (li >> 2)) & 3;
    for (int t = 0; t < 32; t++) {
        const int half = t >> 4;
        const int nt = t + 1;
        if (nt < 32) {
            stage_B(buf ^ 1, xh, xl, (nt >> 4) * 256, (nt & 15) * 32);
            stage_A(buf ^ 1, (nt & 15) * 32);
        }
        bf16x8 ah = bc16(&sA[buf][0][li * 32 + ((ks ^ fsa)) * 8]);
        bf16x8 al = bc16(&sA[buf][1][li * 32 + ((ks ^ fsa)) * 8]);
        bf16x8 bh[2], bl[2];
#pragma unroll
        for (int ni = 0; ni < 2; ni++) {
            const int r = w * 32 + ni * 16 + li;
            const int fs = (r + (r >> 2)) & 3;
            bh[ni] = bc16(&sB[buf][0][r * 32 + ((ks ^ fs)) * 8]);
            bl[ni] = bc16(&sB[buf][1][r * 32 + ((ks ^ fs)) * 8]);
        }
#pragma unroll
        for (int ni = 0; ni < 2; ni++) acc[half * 2 + ni] = mfma16(ah, bh[ni], acc[half * 2 + ni]);
#pragma unroll
        for (int ni = 0; ni < 2; ni++) acc[half * 2 + ni] = mfma16(ah, bl[ni], acc[half * 2 + ni]);
#pragma unroll
        for (int ni = 0; ni < 2; ni++) acc[half * 2 + ni] = mfma16(al, bh[ni], acc[half * 2 + ni]);
        __syncthreads();
        buf ^= 1;
    }

    stage_B(buf, xTh, xTl, 0, 0);

    float M[4], S[4];
#pragma unroll
    for (int r4 = 0; r4 < 4; r4++) {
        float m = acc[0][r4];
#pragma unroll
        for (int i = 1; i < 4; i++) m = fmaxf(m, acc[i][r4]);
#pragma unroll
        for (int o = 1; o < 16; o <<= 1) m = fmaxf(m, __shfl_xor(m, o));
        M[r4] = m;
    }
    if (li == 0) {
#pragma unroll
        for (int r4 = 0; r4 < 4; r4++) redm[w][ks * 4 + r4] = M[r4];
    }
    __syncthreads();
#pragma unroll
    for (int r4 = 0; r4 < 4; r4++) {
        float m = redm[0][ks * 4 + r4];
#pragma unroll
        for (int ww = 1; ww < 8; ww++) m = fmaxf(m, redm[ww][ks * 4 + r4]);
        M[r4] = m;
    }
#pragma unroll
    for (int i = 0; i < 4; i++)
#pragma unroll
        for (int r4 = 0; r4 < 4; r4++) acc[i][r4] = expf(acc[i][r4] - M[r4]);
#pragma unroll
    for (int r4 = 0; r4 < 4; r4++) {
        float s = 0.f;
#pragma unroll
        for (int i = 0; i < 4; i++) s += acc[i][r4];
#pragma unroll
        for (int o = 1; o < 16; o <<= 1) s += __shfl_xor(s, o);
        S[r4] = s;
    }
    if (li == 0) {
#pragma unroll
        for (int r4 = 0; r4 < 4; r4++) reds[w][ks * 4 + r4] = S[r4];
    }
    __syncthreads();
#pragma unroll
    for (int r4 = 0; r4 < 4; r4++) {
        float s = 0.f;
#pragma unroll
        for (int ww = 0; ww < 8; ww++) s += reds[ww][ks * 4 + r4];
        S[r4] = 1.f / s;
    }
#pragma unroll
    for (int i = 0; i < 4; i++) {
        const int hf = i >> 1, ni = i & 1;
        const int s = hf * 256 + w * 32 + ni * 16 + li;
        const int kt = s >> 5, kks = (s >> 3) & 3, j = s & 7;
#pragma unroll
        for (int r4 = 0; r4 < 4; r4++) {
            const int row = ks * 4 + r4;
            const int fs = (row + (row >> 2)) & 3;
            unsigned short h, l2; split2(acc[i][r4] * S[r4], h, l2);
            sP[0][kt][row][(kks ^ fs) * 8 + j] = h;
            sP[1][kt][row][(kks ^ fs) * 8 + j] = l2;
        }
    }
    __syncthreads();

    f32x4 acc2[4];
#pragma unroll
    for (int i = 0; i < 4; i++) acc2[i] = f32x4{0.f, 0.f, 0.f, 0.f};
    for (int t = 0; t < 32; t++) {
        const int half = t >> 4, kt = t & 15;
        const int nt = t + 1;
        if (nt < 32) stage_B(buf ^ 1, xTh, xTl, (nt >> 4) * 256, (nt & 15) * 32);
        bf16x8 ph = bc16(&sP[0][kt][li][(ks ^ fsa) * 8]);
        bf16x8 pl = bc16(&sP[1][kt][li][(ks ^ fsa) * 8]);
        bf16x8 bh[2], bl[2];
#pragma unroll
        for (int ni = 0; ni < 2; ni++) {
            const int r = w * 32 + ni * 16 + li;
            const int fs = (r + (r >> 2)) & 3;
            bh[ni] = bc16(&sB[buf][0][r * 32 + ((ks ^ fs)) * 8]);
            bl[ni] = bc16(&sB[buf][1][r * 32 + ((ks ^ fs)) * 8]);
        }
#pragma unroll
        for (int ni = 0; ni < 2; ni++) acc2[half * 2 + ni] = mfma16(ph, bh[ni], acc2[half * 2 + ni]);
#pragma unroll
        for (int ni = 0; ni < 2; ni++) acc2[half * 2 + ni] = mfma16(ph, bl[ni], acc2[half * 2 + ni]);
#pragma unroll
        for (int ni = 0; ni < 2; ni++) acc2[half * 2 + ni] = mfma16(pl, bh[ni], acc2[half * 2 + ni]);
        __syncthreads();
        buf ^= 1;
    }

#pragma unroll
    for (int i = 0; i < 4; i++) {
        const int hf = i >> 1, ni = i & 1;
        const int n = hf * 256 + w * 32 + ni * 16 + li;
#pragma unroll
        for (int r4 = 0; r4 < 4; r4++) {
            const int m = r0 + ks * 4 + r4;
            const long id = ((long)b * 4 + (m & 3)) * 4096 + (long)(m >> 2) * 512 + n;
            unsigned short h, l2; split2(acc2[i][r4], h, l2);
            U_h[id] = h; U_l[id] = l2;
        }
    }
}

// ---------------------------------------------------------------------------
// Fused FFN (round-10 proven, unchanged): block (cx in [0,32), by row-block).
// ---------------------------------------------------------------------------
__global__ __launch_bounds__(256)
void ffn_fused(const unsigned short* __restrict__ q_h, const unsigned short* __restrict__ q_l,
               const unsigned short* __restrict__ W1T_h, const unsigned short* __restrict__ W1T_l,
               const float* __restrict__ b1,
               const unsigned short* __restrict__ W2T_h, const unsigned short* __restrict__ W2T_l,
               float* __restrict__ parts)
{
    __shared__ __align__(16) unsigned short sA[2 * 1024];
    __shared__ __align__(16) unsigned short sB[2 * 4096];
    __shared__ __align__(16) unsigned short sB2[8192];
    __shared__ __align__(16) unsigned short sF[2][2][16][32];
    const int cx = blockIdx.x, m0 = blockIdx.y * 16;
    const int tid = threadIdx.x, lane = tid & 63, w = tid >> 6;
    const int li = lane & 15, ks = lane >> 4;
    const int n0 = cx * 64;

    auto stageB1 = [&](int buf, int k0) {
#pragma unroll
        for (int i = 0; i < 2; i++) {
            const int c = tid + 256 * i;
            const int p = c >> 8, cc = c & 255, r = cc >> 2, sl = cc & 3;
            const int fs = (r + (r >> 2)) & 3;
            const unsigned short* g = (p ? W1T_l : W1T_h) + (long)(n0 + r) * 512 + k0 + (sl ^ fs) * 8;
            gload16(g, sB + buf * 4096 + p * 2048 + r * 32 + sl * 8);
        }
    };
    auto stageA1 = [&](int buf, int k0) {
        if (tid < 128) {
            const int p = tid >> 6, c = tid & 63, r = c >> 2, sl = c & 3;
            const int fs = (r + (r >> 2)) & 3;
            const unsigned short* g = (p ? q_l : q_h) + (long)(m0 + r) * 512 + k0 + (sl ^ fs) * 8;
            gload16(g, sA + buf * 1024 + p * 512 + r * 32 + sl * 8);
        }
    };

    f32x4 acc = f32x4{0.f, 0.f, 0.f, 0.f};
    int buf = 0;
    stageB1(0, 0); stageA1(0, 0);
    __syncthreads();
    const int fsa = (li + (li >> 2)) & 3;
    for (int kt = 0; kt < 16; kt++) {
        if (kt + 1 < 16) { stageB1(buf ^ 1, (kt + 1) * 32); stageA1(buf ^ 1, (kt + 1) * 32); }
        bf16x8 ah = bc16(sA + buf * 1024 + li * 32 + ((ks ^ fsa)) * 8);
        bf16x8 al = bc16(sA + buf * 1024 + 512 + li * 32 + ((ks ^ fsa)) * 8);
        const int r = w * 16 + li;
        const int fs = (r + (r >> 2)) & 3;
        bf16x8 bh = bc16(sB + buf * 4096 + r * 32 + ((ks ^ fs)) * 8);
        bf16x8 bl = bc16(sB + buf * 4096 + 2048 + r * 32 + ((ks ^ fs)) * 8);
        acc = mfma16(ah, bh, acc);
        acc = mfma16(ah, bl, acc);
        acc = mfma16(al, bh, acc);
        __syncthreads();
        buf ^= 1;
    }

#pragma unroll
    for (int r4 = 0; r4 < 4; r4++) {
        const int row = ks * 4 + r4;
        const int fs = (row + (row >> 2)) & 3;
        const int n = w * 16 + li;
        float v = acc[r4] + b1[n0 + n];
        v = 0.5f * v * (1.f + erff(v * 0.70710678118654752f));
        const int kt = n >> 5, kks = (n >> 3) & 3, j = n & 7;
        unsigned short h, l2; split2(v, h, l2);
        sF[0][kt][row][(kks ^ fs) * 8 + j] = h;
        sF[1][kt][row][(kks ^ fs) * 8 + j] = l2;
    }
    __syncthreads();

    for (int nc = 0; nc < 4; nc++) {
        f32x4 acc2[2];
#pragma unroll
        for (int j = 0; j < 2; j++) acc2[j] = f32x4{0.f, 0.f, 0.f, 0.f};
        for (int kt2 = 0; kt2 < 2; kt2++) {
            __syncthreads();
#pragma unroll
            for (int i = 0; i < 4; i++) {
                const int c = tid + 256 * i;
                const int p = c >> 9, cc = c & 511, r = cc >> 2, sl = cc & 3;
                const int fs = (r + (r >> 2)) & 3;
                const unsigned short* g = (p ? W2T_l : W2T_h)
                    + (long)(nc * 128 + r) * 2048 + cx * 64 + kt2 * 32 + (sl ^ fs) * 8;
                gload16(g, sB2 + p * 4096 + r * 32 + sl * 8);
            }
            __syncthreads();
            bf16x8 fh, fl, bh[2], bl[2];
            {
                const int row = li;
                const int fs = (row + (row >> 2)) & 3;
                fh = bc16(&sF[0][kt2][row][(ks ^ fs) * 8]);
                fl = bc16(&sF[1][kt2][row][(ks ^ fs) * 8]);
            }
#pragma unroll
            for (int ni = 0; ni < 2; ni++) {
                const int r = w * 32 + ni * 16 + li;
                const int fs = (r + (r >> 2)) & 3;
                bh[ni] = bc16(sB2 + r * 32 + (ks ^ fs) * 8);
                bl[ni] = bc16(sB2 + 4096 + r * 32 + (ks ^ fs) * 8);
            }
#pragma unroll
            for (int ni = 0; ni < 2; ni++) acc2[ni] = mfma16(fh, bh[ni], acc2[ni]);
#pragma unroll
            for (int ni = 0; ni < 2; ni++) acc2[ni] = mfma16(fh, bl[ni], acc2[ni]);
#pragma unroll
            for (int ni = 0; ni < 2; ni++) acc2[ni] = mfma16(fl, bh[ni], acc2[ni]);
        }
#pragma unroll
        for (int r4 = 0; r4 < 4; r4++) {
            const int m = m0 + ks * 4 + r4;
#pragma unroll
            for (int ni = 0; ni < 2; ni++) {
                const int n2 = nc * 128 + w * 32 + ni * 16 + li;
                parts[(long)cx * 131072 + (long)m * 512 + n2] = acc2[ni][r4];
            }
        }
    }
}

// ===========================================================================
// Prep bodies + merged prep kernels (round-10 proven)
// ===========================================================================

__device__ void prepT_body(float* t, int bx, int by, int z,
                           const float* __restrict__ in,
                           unsigned short* __restrict__ Th, unsigned short* __restrict__ Tl,
                           int ldin, int ldo, long inStride, long outStride)
{
    const int n0 = bx * 64, k0 = by * 64;
    const int tid = threadIdx.x;
    const float* src = in + (long)z * inStride;
#pragma unroll
    for (int i = 0; i < 4; i++) {
        int ch = tid + 256 * i;
        int r = ch >> 4, q = ch & 15;
        float4 v = *(const float4*)(src + (long)(k0 + r) * ldin + n0 + q * 4);
        t[r * 68 + q * 4 + 0] = v.x; t[r * 68 + q * 4 + 1] = v.y;
        t[r * 68 + q * 4 + 2] = v.z; t[r * 68 + q * 4 + 3] = v.w;
    }
    __syncthreads();
#pragma unroll
    for (int i = 0; i < 4; i++) {
        int ch = tid + 256 * i;
        int rc = ch >> 4, qk = ch & 15;
        union { uint2 v; unsigned short u[4]; } oh, ol;
#pragma unroll
        for (int j = 0; j < 4; j++) split2(t[(qk * 4 + j) * 68 + rc], oh.u[j], ol.u[j]);
        long o = (long)z * outStride + (long)(n0 + rc) * ldo + k0 + qk * 4;
        *(uint2*)(Th + o) = oh.v;
        *(uint2*)(Tl + o) = ol.v;
    }
}

__device__ void t32_body(float* t, int bx, int by, int z,
                         const float* __restrict__ in, float* __restrict__ out, long zstr)
{
    const int c0 = bx * 64, r0 = by * 64;
    const int tid = threadIdx.x;
#pragma unroll
    for (int i = 0; i < 4; i++) {
        int ch = tid + 256 * i;
        int r = ch >> 4, q = ch & 15;
        float4 v = *(const float4*)(in + (long)z * zstr + (long)(r0 + r) * 512 + c0 + q * 4);
        t[r * 65 + q * 4 + 0] = v.x; t[r * 65 + q * 4 + 1] = v.y;
        t[r * 65 + q * 4 + 2] = v.z; t[r * 65 + q * 4 + 3] = v.w;
    }
    __syncthreads();
#pragma unroll
    for (int i = 0; i < 4; i++) {
        int ch = tid + 256 * i;
        int rc = ch >> 4, qk = ch & 15;
        float4 o;
        o.x = t[(qk * 4 + 0) * 65 + rc]; o.y = t[(qk * 4 + 1) * 65 + rc];
        o.z = t[(qk * 4 + 2) * 65 + rc]; o.w = t[(qk * 4 + 3) * 65 + rc];
        *(float4*)(out + (long)z * zstr + (long)(c0 + rc) * 512 + r0 + qk * 4) = o;
    }
}

__global__ __launch_bounds__(256)
void big_prep(const float* projW, unsigned short* pwT_h, unsigned short* pwT_l,
              const float* W1, unsigned short* W1T_h, unsigned short* W1T_l,
              const float* W2, unsigned short* W2T_h, unsigned short* W2T_l,
              const float* Wo, float* WoT)
{
    __shared__ float t[64 * 68];
    const int bid = blockIdx.x;
    if (bid < 128) {
        prepT_body(t, bid & 7, bid >> 3, 0, projW, pwT_h, pwT_l, 512, 1024, 0, 0);
    } else if (bid < 1152) {
        int u = bid - 128;
        prepT_body(t, u & 31, (u >> 5) & 7, u >> 8, W1, W1T_h, W1T_l, 2048, 512, 1048576, 1048576);
    } else if (bid < 2176) {
        int u = bid - 1152;
        prepT_body(t, u & 7, (u >> 3) & 31, u >> 8, W2, W2T_h, W2T_l, 512, 2048, 1048576, 1048576);
    } else {
        int u = bid - 2176;
        t32_body(t, u & 7, (u >> 3) & 7, u >> 6, Wo, WoT, 262144);
    }
}

__device__ void w2_body(unsigned short* sA, unsigned short* sB, int bx, int by, int z,
                        const float* A_, const float* B_, float scale,
                        unsigned short* Th, unsigned short* Tl,
                        long zsA, long zsB, long S1, long S2, long SMs)
{
    const int tid = threadIdx.x;
    const int m0 = by * 128, n0 = bx * 128;
    const int lane = tid & 63, w = tid >> 6, wr = w >> 1, wc = w & 1;
    const float* Ab = A_ + (long)(z >> 3) * zsA + (z & 7) * 64;
    const float* Bb = B_ + (long)(z >> 3) * zsB + (z & 7) * 64;

    f32x4 acc[4][4];
#pragma unroll
    for (int i = 0; i < 4; i++)
#pragma unroll
        for (int j = 0; j < 4; j++) acc[i][j] = f32x4{0.f, 0.f, 0.f, 0.f};

    for (int k0 = 0; k0 < 64; k0 += 32) {
        __syncthreads();
#pragma unroll
        for (int op = 0; op < 2; op++) {
            const float* src0 = op ? Bb : Ab;
            unsigned short* dst = op ? sB : sA;
#pragma unroll
            for (int i = 0; i < 2; i++) {
                const int c = tid + 256 * i;
                const int r = c >> 2, s = c & 3;
                const int fs = (r + (r >> 2)) & 3;
                const float* src = src0 + (long)((op ? n0 : m0) + r) * 512 + k0 + s * 8;
                float4 v0 = *(const float4*)src;
                float4 v1 = *(const float4*)(src + 4);
                float vv[8] = {v0.x, v0.y, v0.z, v0.w, v1.x, v1.y, v1.z, v1.w};
                union { s16x8 v; unsigned short u[8]; } hh, ll;
#pragma unroll
                for (int j = 0; j < 8; j++) split2(vv[j], hh.u[j], ll.u[j]);
                *(s16x8*)&dst[0 * 4096 + r * 32 + (s ^ fs) * 8] = hh.v;
                *(s16x8*)&dst[1 * 4096 + r * 32 + (s ^ fs) * 8] = ll.v;
            }
        }
        __syncthreads();
        const int li = lane & 15, ks = lane >> 4;
        bf16x8 ah[4], al[4], bh[4], bl[4];
#pragma unroll
        for (int mi = 0; mi < 4; mi++) {
            const int r = wr * 64 + mi * 16 + li;
            const int fs = (r + (r >> 2)) & 3;
            ah[mi] = bc16(sA + r * 32 + (ks ^ fs) * 8);
            al[mi] = bc16(sA + 4096 + r * 32 + (ks ^ fs) * 8);
        }
#pragma unroll
        for (int ni = 0; ni < 4; ni++) {
            const int r = wc * 64 + ni * 16 + li;
            const int fs = (r + (r >> 2)) & 3;
            bh[ni] = bc16(sB + r * 32 + (ks ^ fs) * 8);
            bl[ni] = bc16(sB + 4096 + r * 32 + (ks ^ fs) * 8);
        }
#pragma unroll
        for (int mi = 0; mi < 4; mi++)
#pragma unroll
            for (int ni = 0; ni < 4; ni++) acc[mi][ni] = mfma16(ah[mi], bh[ni], acc[mi][ni]);
#pragma unroll
        for (int mi = 0; mi < 4; mi++)
#pragma unroll
            for (int ni = 0; ni < 4; ni++) acc[mi][ni] = mfma16(ah[mi], bl[ni], acc[mi][ni]);
#pragma unroll
        for (int mi = 0; mi < 4; mi++)
#pragma unroll
            for (int ni = 0; ni < 4; ni++) acc[mi][ni] = mfma16(al[mi], bh[ni], acc[mi][ni]);
    }
#pragma unroll
    for (int mi = 0; mi < 4; mi++)
#pragma unroll
        for (int r4 = 0; r4 < 4; r4++) {
            const int m = m0 + wr * 64 + mi * 16 + (lane >> 4) * 4 + r4;
#pragma unroll
            for (int ni = 0; ni < 4; ni++) {
                const int n = n0 + wc * 64 + ni * 16 + (lane & 15);
                float v = acc[mi][ni][r4] * scale;
                unsigned short h, l; split2(v, h, l);
                long id = (long)(z >> 3) * S1 + (long)(z & 7) * S2 + (long)m * SMs + n;
                Th[id] = h; Tl[id] = l;
            }
        }
}

__global__ __launch_bounds__(256)
void w2_merged(const float* Wk, const float* Wq,
               unsigned short* MT_h, unsigned short* MT_l,
               const float* WoT, const float* Wv,
               unsigned short* WVOT_h, unsigned short* WVOT_l)
{
    __shared__ __align__(16) unsigned short sA[2 * 4096];
    __shared__ __align__(16) unsigned short sB[2 * 4096];
    const int bid = blockIdx.x;
    if (bid < 512) {
        w2_body(sA, sB, bid & 3, (bid >> 2) & 3, bid >> 4, Wk, Wq, 0.125f, MT_h, MT_l,
                262144, 262144, 2097152, 262144, 512);
    } else {
        int u = bid - 512;
        w2_body(sA, sB, u & 3, (u >> 2) & 3, u >> 4, WoT, Wv, 1.f, WVOT_h, WVOT_l,
                262144, 262144, 2097152, 512, 4096);
    }
}

__global__ __launch_bounds__(256)
void small_prep(const float* cbook, float* cbT, float* cn,
                const float* bq, const float* Wk, float* biasA,
                const float* bv, const float* Wo, const float* bo, float* biasO,
                const float* qt, float* q, unsigned short* qh_s, unsigned short* ql_s)
{
    __shared__ float sm[256];
    const int bid = blockIdx.x, tid = threadIdx.x;
    if (bid < 768) {
        const int rowi = bid, l = rowi >> 8, j = rowi & 255;
        const float* row = cbook + (long)rowi * 512;
        float v0 = row[tid], v1 = row[tid + 256];
        cbT[(long)l * 131072 + (long)tid * 256 + j]         = v0;
        cbT[(long)l * 131072 + (long)(tid + 256) * 256 + j] = v1;
        float s = v0 * v0 + v1 * v1;
#pragma unroll
        for (int o = 32; o > 0; o >>= 1) s += __shfl_xor(s, o);
        if ((tid & 63) == 0) sm[tid >> 6] = s;
        __syncthreads();
        if (tid == 0) cn[rowi] = sm[0] + sm[1] + sm[2] + sm[3];
    } else if (bid < 832) {
        const int gid = (bid - 768) * 256 + tid;
        const int l = gid >> 12, hc = gid & 4095, h = hc >> 9, c = hc & 511;
        const float* b = bq + l * 512 + h * 64;
        const float* w = Wk + (long)l * 262144 + (long)c * 512 + h * 64;
        float s = 0.f;
#pragma unroll 16
        for (int d = 0; d < 64; d++) s = fmaf(b[d], w[d], s);
        biasA[gid] = 0.125f * s;
    } else if (bid < 864) {
        const int u = bid - 832;
        const int l = u >> 3, oc = u & 7;
        const int o = oc * 64 + (tid & 63), j4 = tid >> 6;
        float acc = 0.f;
        for (int j = j4; j < 512; j += 4)
            acc = fmaf(bv[l * 512 + j], Wo[(long)l * 262144 + (long)j * 512 + o], acc);
        sm[j4 * 64 + (tid & 63)] = acc;
        __syncthreads();
        if (tid < 64) {
            float s = sm[tid] + sm[64 + tid] + sm[128 + tid] + sm[192 + tid]
                    + bo[l * 512 + oc * 64 + tid];
            biasO[l * 512 + oc * 64 + tid] = s;
        }
    } else {
        const int r = bid - 864, t = r & 3;
        const long base = (long)r * 512;
        float a = qt[t * 512 + tid], c = qt[t * 512 + 256 + tid];
        q[base + tid] = a; q[base + 256 + tid] = c;
        unsigned short h, l;
        split2(a, h, l); qh_s[base + tid] = h;       ql_s[base + tid] = l;
        split2(c, h, l); qh_s[base + tid + 256] = h; ql_s[base + tid + 256] = l;
    }
}

// ---- q = LayerNorm(q + sum_z parts[z] + bias)*g + b; emit split q ----------
__global__ __launch_bounds__(256) void add_ln_sum(float* __restrict__ q,
                                                  const float* __restrict__ parts, int np,
                                                  const float* __restrict__ bias,
                                                  const float* __restrict__ g,
                                                  const float* __restrict__ b,
                                                  unsigned short* __restrict__ qh_s,
                                                  unsigned short* __restrict__ ql_s)
{
    __shared__ float red[4];
    const int tid = threadIdx.x;
    const long base = (long)blockIdx.x * 512;
    float* row = q + base;
    float v0 = row[tid] + bias[tid];
    float v1 = row[tid + 256] + bias[tid + 256];
    for (int z = 0; z < np; z++) {
        v0 += parts[(long)z * 131072 + base + tid];
        v1 += parts[(long)z * 131072 + base + tid + 256];
    }
    float s = v0 + v1;
#pragma unroll
    for (int o = 32; o > 0; o >>= 1) s += __shfl_xor(s, o);
    if ((tid & 63) == 0) red[tid >> 6] = s;
    __syncthreads();
    float mu = (red[0] + red[1] + red[2] + red[3]) * (1.f / 512.f);
    __syncthreads();
    float c0 = v0 - mu, c1 = v1 - mu;
    float sq = c0 * c0 + c1 * c1;
#pragma unroll
    for (int o = 32; o > 0; o >>= 1) sq += __shfl_xor(sq, o);
    if ((tid & 63) == 0) red[tid >> 6] = sq;
    __syncthreads();
    float var = (red[0] + red[1] + red[2] + red[3]) * (1.f / 512.f);
    float rs = rsqrtf(var + 1e-5f);
    float o0 = c0 * rs * g[tid] + b[tid];
    float o1 = c1 * rs * g[tid + 256] + b[tid + 256];
    row[tid] = o0; row[tid + 256] = o1;
    unsigned short h, l;
    split2(o0, h, l); qh_s[base + tid] = h;       ql_s[base + tid] = l;
    split2(o1, h, l); qh_s[base + tid + 256] = h; ql_s[base + tid + 256] = l;
}

__global__ __launch_bounds__(256) void rq_kernel(const float* __restrict__ qf,
                                                 const float* __restrict__ cb,
                                                 const float* __restrict__ cbT,
                                                 const float* __restrict__ cn,
                                                 float* __restrict__ out)
{
    __shared__ float r[512], rec[512];
    __shared__ float rd[4]; __shared__ int ri[4];
    __shared__ int sids[3];
    const int p = blockIdx.x, tid = threadIdx.x;
    r[tid]         = qf[(long)p * 512 + tid];
    r[tid + 256]   = qf[(long)p * 512 + 256 + tid];
    rec[tid] = 0.f; rec[tid + 256] = 0.f;
    __syncthreads();
    for (int l = 0; l < 3; l++) {
        const float* ct = cbT + (long)l * 131072;
        float dot = 0.f;
#pragma unroll 8
        for (int k = 0; k < 512; k++) dot = fmaf(r[k], ct[(long)k * 256 + tid], dot);
        float d2 = cn[l * 256 + tid] - 2.f * dot;
        int idx = tid;
#pragma unroll
        for (int o = 32; o > 0; o >>= 1) {
            float od = __shfl_xor(d2, o); int oi = __shfl_xor(idx, o);
            if (od < d2 || (od == d2 && oi < idx)) { d2 = od; idx = oi; }
        }
        if ((tid & 63) == 0) { rd[tid >> 6] = d2; ri[tid >> 6] = idx; }
        __syncthreads();
        if (tid == 0) {
            float bd = rd[0]; int bb = ri[0];
            for (int w = 1; w < 4; w++)
                if (rd[w] < bd || (rd[w] == bd && ri[w] < bb)) { bd = rd[w]; bb = ri[w]; }
            sids[l] = bb;
        }
        __syncthreads();
        const float* crow = cb + ((long)l * 256 + sids[l]) * 512;
        float c0 = crow[tid], c1 = crow[tid + 256];
        r[tid] -= c0; rec[tid] += c0;
        r[tid + 256] -= c1; rec[tid + 256] += c1;
        __syncthreads();
    }
    float* orec = out + 768 + (long)p * 512;
    orec[tid] = rec[tid]; orec[tid + 256] = rec[tid + 256];
    if (tid < 3) out[p * 3 + tid] = (float)sids[tid];
}

// ---------------------------------------------------------------------------
extern "C" void kernel_launch(void* const* d_in, const int* in_sizes, int n_in,
                              void* d_out, int out_size, void* d_ws, size_t ws_size,
                              hipStream_t stream)
{
    const float* mm    = (const float*)d_in[0];
    const float* projW = (const float*)d_in[1];
    const float* projb = (const float*)d_in[2];
    const float* qt    = (const float*)d_in[3];
    const float* Wq    = (const float*)d_in[4];
    const float* bq    = (const float*)d_in[5];
    const float* Wk    = (const float*)d_in[6];
    const float* Wv    = (const float*)d_in[8];
    const float* bv    = (const float*)d_in[9];
    const float* Wo    = (const float*)d_in[10];
    const float* bo    = (const float*)d_in[11];
    const float* W1    = (const float*)d_in[12];
    const float* b1    = (const float*)d_in[13];
    const float* W2    = (const float*)d_in[14];
    const float* b2    = (const float*)d_in[15];
    const float* lng   = (const float*)d_in[16];
    const float* lnb   = (const float*)d_in[17];
    const float* cbook = (const float*)d_in[18];

    char* p = (char*)d_ws;
    auto alloc = [&](size_t bytes) { char* r = p; p += (bytes + 255) & ~(size_t)255; return r; };
    unsigned short* x_h   = (unsigned short*)alloc(16777216ull * 2);
    unsigned short* x_l   = (unsigned short*)alloc(16777216ull * 2);
    unsigned short* xT_h  = (unsigned short*)alloc(16777216ull * 2);
    unsigned short* xT_l  = (unsigned short*)alloc(16777216ull * 2);
    unsigned short* pwT_h = (unsigned short*)alloc(524288ull * 2);
    unsigned short* pwT_l = (unsigned short*)alloc(524288ull * 2);
    unsigned short* MT_h  = (unsigned short*)alloc(8388608ull * 2);
    unsigned short* MT_l  = (unsigned short*)alloc(8388608ull * 2);
    unsigned short* WVOT_h= (unsigned short*)alloc(8388608ull * 2);
    unsigned short* WVOT_l= (unsigned short*)alloc(8388608ull * 2);
    float*          WoT   = (float*)alloc(1048576ull * 4);
    unsigned short* W1T_h = (unsigned short*)alloc(4194304ull * 2);
    unsigned short* W1T_l = (unsigned short*)alloc(4194304ull * 2);
    unsigned short* W2T_h = (unsigned short*)alloc(4194304ull * 2);
    unsigned short* W2T_l = (unsigned short*)alloc(4194304ull * 2);
    unsigned short* A_h   = (unsigned short*)alloc(1048576ull * 2);
    unsigned short* A_l   = (unsigned short*)alloc(1048576ull * 2);
    unsigned short* U_h   = (unsigned short*)alloc(1048576ull * 2);
    unsigned short* U_l   = (unsigned short*)alloc(1048576ull * 2);
    unsigned short* q_h   = (unsigned short*)alloc(131072ull * 2);
    unsigned short* q_l   = (unsigned short*)alloc(131072ull * 2);
    float* parts = (float*)alloc(32ull * 131072 * 4);
    float* q     = (float*)alloc(131072ull * 4);
    float* cbT   = (float*)alloc(393216ull * 4);
    float* cn    = (float*)alloc(768ull * 4);
    float* biasA = (float*)alloc(16384ull * 4);
    float* biasO = (float*)alloc(2048ull * 4);

    // ---- merged one-time preps (3 dispatches) ----
    big_prep<<<2432, 256, 0, stream>>>(projW, pwT_h, pwT_l, W1, W1T_h, W1T_l,
                                       W2, W2T_h, W2T_l, Wo, WoT);
    w2_merged<<<1024, 256, 0, stream>>>(Wk, Wq, MT_h, MT_l, WoT, Wv, WVOT_h, WVOT_l);
    small_prep<<<1120, 256, 0, stream>>>(cbook, cbT, cn, bq, Wk, biasA,
                                         bv, Wo, bo, biasO, qt, q, q_h, q_l);

    // ---- x = mm @ projW + projb (split out + direct xT writes) ----
    mfma_gemm<128, 4, 4, 2, 2, 1, 1, 0, false, true, true><<<dim3(4, 256, 1), 256, 0, stream>>>(
        mm, nullptr, pwT_h, pwT_l, projb, x_h, x_l, 1024, 1024, 1024, 512, 0, 0, 0, xT_h, xT_l);

    for (int i = 0; i < 4; i++) {
        const unsigned short* MTh = MT_h + (long)i * 2097152;
        const unsigned short* MTl = MT_l + (long)i * 2097152;
        const unsigned short* WVh = WVOT_h + (long)i * 2097152;
        const unsigned short* WVl = WVOT_l + (long)i * 2097152;
        const unsigned short* W1h = W1T_h + (long)i * 1048576;
        const unsigned short* W1l = W1T_l + (long)i * 1048576;
        const unsigned short* W2h = W2T_h + (long)i * 1048576;
        const unsigned short* W2l = W2T_l + (long)i * 1048576;
        const float* b1i = b1 + i * 2048; const float* b2i = b2 + i * 512;
        const float* gi  = lng + i * 512; const float* bi_ = lnb + i * 512;

        // A[b][ht][c] = q @ MT + biasA   (BM=16: 512 blocks)
        mfma_gemm<16, 1, 2, 1, 4, 0, 1, 1, false, false, false><<<dim3(32, 16, 1), 256, 0, stream>>>(
            q_h, q_l, MTh, MTl, biasA + i * 4096, A_h, A_l, 512, 512, 512, 512, 0, 0, 0,
            nullptr, nullptr);
        // fused scores -> softmax -> U
        fused_attn<<<dim3(2, 64), 512, 0, stream>>>(A_h, A_l, x_h, x_l, xT_h, xT_l, U_h, U_l);
        // attn_out partials = U @ WVOT  (BM=16, split-K 8: 512 blocks)
        mfma_gemm<16, 1, 2, 1, 4, 0, 0, 0, false, false, false><<<dim3(4, 16, 8), 256, 0, stream>>>(
            U_h, U_l, WVh, WVl, nullptr, parts, nullptr, 512, 4096, 4096, 512,
            512, 512, 131072, nullptr, nullptr);
        add_ln_sum<<<256, 256, 0, stream>>>(q, parts, 8, biasO + i * 512, gi, bi_, q_h, q_l);
        // fused ffn1+ffn2 -> 32 partials (512 blocks)
        ffn_fused<<<dim3(32, 16), 256, 0, stream>>>(q_h, q_l, W1h, W1l, b1i, W2h, W2l, parts);
        add_ln_sum<<<256, 256, 0, stream>>>(q, parts, 32, b2i, gi, bi_, q_h, q_l);
    }

    rq_kernel<<<256, 256, 0, stream>>>(q, cbook, cbT, cn, (float*)d_out);
}

// Round 13
// 858.293 us; speedup vs baseline: 1.0559x; 1.0319x over previous
//
#include <hip/hip_runtime.h>
#include <math.h>

// ---------------------------------------------------------------------------
// OneRecTokenizer. B=64 S=512 MM=1024 HID=512 T=4 NL=4 NHEAD=8 DH=64 RQ_L=3 CB=256
// Round 13: exact revert to the round-10 configuration (871us, best measured).
// A/B ledger r10-r12 showed XTW/pre-split variants shuffle ~213us of proj+xT
// work without net gain; this is the proven optimum arrangement.
// bf16x2 3-pass split everywhere: A*B ~= Ah*Bh + Ah*Bl + Al*Bh (rel err ~2^-17).
// ---------------------------------------------------------------------------

typedef __attribute__((ext_vector_type(8))) short   s16x8;
typedef __attribute__((ext_vector_type(8))) __bf16  bf16x8;
typedef __attribute__((ext_vector_type(4))) float   f32x4;

__device__ __forceinline__ void split2(float v, unsigned short& hi, unsigned short& lo) {
    unsigned u = __builtin_bit_cast(unsigned, v);
    hi = (unsigned short)(u >> 16);
    float hf = __builtin_bit_cast(float, u & 0xffff0000u);
    float l = v - hf;
    unsigned ul = __builtin_bit_cast(unsigned, l);
    lo = (unsigned short)((ul + 0x7fffu + ((ul >> 16) & 1u)) >> 16);
}

__device__ __forceinline__ f32x4 mfma16(bf16x8 a, bf16x8 b, f32x4 c) {
    return __builtin_amdgcn_mfma_f32_16x16x32_bf16(a, b, c, 0, 0, 0);
}

__device__ __forceinline__ void gload16(const void* g, void* l) {
    __builtin_amdgcn_global_load_lds(
        (const __attribute__((address_space(1))) unsigned*)g,
        (__attribute__((address_space(3))) unsigned*)l, 16, 0, 0);
}

__device__ __forceinline__ bf16x8 bc16(const unsigned short* p) {
    return __builtin_bit_cast(bf16x8, *(const s16x8*)p);
}

// ---------------------------------------------------------------------------
// Unified bf16x2 3-pass MFMA GEMM. BN=128. AMODE 0: A split bf16 (BM 16/32,
// gload_lds); AMODE 1: A fp32 split on the fly (BM=128, proj).
// ---------------------------------------------------------------------------
template<int BM, int FM, int FN, int WR, int WC, int AMODE, int OMODE,
         int IDX, bool GELU, bool SWZ>
__global__ __launch_bounds__(256)
void mfma_gemm(const void* __restrict__ Ah_, const void* __restrict__ Al_,
               const unsigned short* __restrict__ Bh_, const unsigned short* __restrict__ Bl_,
               const float* __restrict__ bias,
               void* __restrict__ Ch_, void* __restrict__ Cl_,
               int K, int lda, int ldb, int ldc,
               long strA, long strB, long strC)
{
    constexpr int BHALF = 8192;
    constexpr int AHALF = 2 * BM * 32;
    __shared__ __align__(16) unsigned short sA[2 * AHALF];
    __shared__ __align__(16) unsigned short sB[2 * BHALF];

    int bx = blockIdx.x, by = blockIdx.y;
    if constexpr (SWZ) {
        int nb = gridDim.x * gridDim.y;
        int h  = bx + gridDim.x * by;
        int orig = (h & 7) * (nb >> 3) + (h >> 3);
        bx = orig % gridDim.x; by = orig / gridDim.x;
    }
    const int tid = threadIdx.x, z = blockIdx.z;
    const int m0 = by * BM, n0 = bx * 128;
    const int lane = tid & 63, w = tid >> 6;
    const int wr = w / WC, wc = w % WC;

    const float* Af = nullptr;
    const unsigned short *Ah = nullptr, *Al = nullptr;
    if constexpr (AMODE == 1) {
        Af = (const float*)Ah_;
    } else {
        Ah = (const unsigned short*)Ah_ + (long)z * strA;
        Al = (const unsigned short*)Al_ + (long)z * strA;
    }
    const unsigned short* Bh = Bh_ + (long)z * strB;
    const unsigned short* Bl = Bl_ + (long)z * strB;

    auto stageB = [&](int buf, int k0) {
#pragma unroll
        for (int i = 0; i < 4; i++) {
            const int c = tid + 256 * i;
            const int p = c >> 9, cc = c & 511, r = cc >> 2, sl = cc & 3;
            const int fs = (r + (r >> 2)) & 3;
            const unsigned short* g = (p ? Bl : Bh) + (long)(n0 + r) * ldb + k0 + ((sl ^ fs)) * 8;
            gload16(g, sB + buf * BHALF + p * 4096 + r * 32 + sl * 8);
        }
    };
    auto stageA = [&](int buf, int k0) {
        if constexpr (AMODE == 0 && BM == 32) {
            const int p = tid >> 7, c = tid & 127, r = c >> 2, sl = c & 3;
            const int fs = (r + (r >> 2)) & 3;
            const unsigned short* g = (p ? Al : Ah) + (long)(m0 + r) * lda + k0 + ((sl ^ fs)) * 8;
            gload16(g, sA + buf * AHALF + p * (BM * 32) + r * 32 + sl * 8);
        } else if constexpr (AMODE == 0 && BM == 16) {
            if (tid < 128) {
                const int p = tid >> 6, c = tid & 63, r = c >> 2, sl = c & 3;
                const int fs = (r + (r >> 2)) & 3;
                const unsigned short* g = (p ? Al : Ah) + (long)(m0 + r) * lda + k0 + ((sl ^ fs)) * 8;
                gload16(g, sA + buf * AHALF + p * (BM * 32) + r * 32 + sl * 8);
            }
        } else {
            const int r = tid >> 1, hh2 = tid & 1;
            const int fs = (r + (r >> 2)) & 3;
            const float* src = Af + (long)(m0 + r) * lda + k0 + hh2 * 16;
#pragma unroll
            for (int s2 = 0; s2 < 2; s2++) {
                const int s = 2 * hh2 + s2;
                float4 v0 = *(const float4*)(src + s2 * 8);
                float4 v1 = *(const float4*)(src + s2 * 8 + 4);
                float vv[8] = {v0.x, v0.y, v0.z, v0.w, v1.x, v1.y, v1.z, v1.w};
                union { s16x8 v; unsigned short u[8]; } hu, lu;
#pragma unroll
                for (int j = 0; j < 8; j++) split2(vv[j], hu.u[j], lu.u[j]);
                *(s16x8*)&sA[buf * AHALF + r * 32 + ((s ^ fs)) * 8] = hu.v;
                *(s16x8*)&sA[buf * AHALF + BM * 32 + r * 32 + ((s ^ fs)) * 8] = lu.v;
            }
        }
    };

    f32x4 acc[FM][FN];
#pragma unroll
    for (int i = 0; i < FM; i++)
#pragma unroll
        for (int j = 0; j < FN; j++) acc[i][j] = f32x4{0.f, 0.f, 0.f, 0.f};

    const int NT = K / 32;
    int buf = 0;
    stageB(0, 0);
    stageA(0, 0);
    __syncthreads();

    const int li = lane & 15, ks = lane >> 4;

    for (int kt = 0; kt < NT; kt++) {
        if (kt + 1 < NT) { stageB(buf ^ 1, (kt + 1) * 32); stageA(buf ^ 1, (kt + 1) * 32); }
        bf16x8 ah[FM], al[FM], bh[FN], bl[FN];
#pragma unroll
        for (int mi = 0; mi < FM; mi++) {
            const int r = wr * (FM * 16) + mi * 16 + li;
            const int fs = (r + (r >> 2)) & 3;
            ah[mi] = bc16(&sA[buf * AHALF + r * 32 + ((ks ^ fs)) * 8]);
            al[mi] = bc16(&sA[buf * AHALF + BM * 32 + r * 32 + ((ks ^ fs)) * 8]);
        }
#pragma unroll
        for (int ni = 0; ni < FN; ni++) {
            const int r = wc * (FN * 16) + ni * 16 + li;
            const int fs = (r + (r >> 2)) & 3;
            bh[ni] = bc16(&sB[buf * BHALF + r * 32 + ((ks ^ fs)) * 8]);
            bl[ni] = bc16(&sB[buf * BHALF + 4096 + r * 32 + ((ks ^ fs)) * 8]);
        }
#pragma unroll
        for (int mi = 0; mi < FM; mi++)
#pragma unroll
            for (int ni = 0; ni < FN; ni++) acc[mi][ni] = mfma16(ah[mi], bh[ni], acc[mi][ni]);
#pragma unroll
        for (int mi = 0; mi < FM; mi++)
#pragma unroll
            for (int ni = 0; ni < FN; ni++) acc[mi][ni] = mfma16(ah[mi], bl[ni], acc[mi][ni]);
#pragma unroll
        for (int mi = 0; mi < FM; mi++)
#pragma unroll
            for (int ni = 0; ni < FN; ni++) acc[mi][ni] = mfma16(al[mi], bh[ni], acc[mi][ni]);
        __syncthreads();
        buf ^= 1;
    }

#pragma unroll
    for (int mi = 0; mi < FM; mi++)
#pragma unroll
        for (int r4 = 0; r4 < 4; r4++) {
            const int m = m0 + wr * (FM * 16) + mi * 16 + (lane >> 4) * 4 + r4;
#pragma unroll
            for (int ni = 0; ni < FN; ni++) {
                const int n = n0 + wc * (FN * 16) + ni * 16 + (lane & 15);
                float v = acc[mi][ni][r4];
                if (bias) v += bias[n];
                if constexpr (GELU) v = 0.5f * v * (1.f + erff(v * 0.70710678118654752f));
                long id;
                if constexpr (IDX == 0)      id = (long)z * strC + (long)m * ldc + n;
                else                         id = ((long)(m >> 2)) * 16384
                                                + (long)((n >> 9) * 4 + (m & 3)) * 512 + (n & 511);
                if constexpr (OMODE == 1) {
                    unsigned short h, l; split2(v, h, l);
                    ((unsigned short*)Ch_)[id] = h;
                    ((unsigned short*)Cl_)[id] = l;
                } else {
                    ((float*)Ch_)[id] = v;
                }
            }
        }
}

// ---------------------------------------------------------------------------
// Fused attention, 512 threads (8 waves). Each wave covers 32 of the 256
// staged B rows: s/c = hf*256 + w*32 + ni*16 + li. XCD pair-swizzle.
// ---------------------------------------------------------------------------
__global__ __launch_bounds__(512)
void fused_attn(const unsigned short* __restrict__ A_h, const unsigned short* __restrict__ A_l,
                const unsigned short* __restrict__ x_h, const unsigned short* __restrict__ x_l,
                const unsigned short* __restrict__ xT_h, const unsigned short* __restrict__ xT_l,
                unsigned short* __restrict__ U_h, unsigned short* __restrict__ U_l)
{
    __shared__ __align__(16) unsigned short sB[2][2][8192];
    __shared__ __align__(16) unsigned short sA[2][2][512];
    __shared__ __align__(16) unsigned short sP[2][16][16][32];
    __shared__ float redm[8][16], reds[8][16];

    const int tid = threadIdx.x;
    const int lin  = blockIdx.x + 2 * blockIdx.y;
    const int orig = (lin & 7) * 16 + (lin >> 3);
    const int b = orig >> 1, r0 = (orig & 1) * 16;
    const int lane = tid & 63, w = tid >> 6;
    const int li = lane & 15, ks = lane >> 4;
    const unsigned short* Ah = A_h + b * 16384 + r0 * 512;
    const unsigned short* Al = A_l + b * 16384 + r0 * 512;
    const unsigned short* xh = x_h + (long)b * 262144;
    const unsigned short* xl = x_l + (long)b * 262144;
    const unsigned short* xTh = xT_h + (long)b * 262144;
    const unsigned short* xTl = xT_l + (long)b * 262144;

    auto stage_B = [&](int buf, const unsigned short* sh, const unsigned short* sl2,
                       int row0, int k0) {
#pragma unroll
        for (int i = 0; i < 4; i++) {
            const int c2 = tid + 512 * i;
            const int p = c2 >> 10, cc = c2 & 1023, r = cc >> 2, sl = cc & 3;
            const int fs = (r + (r >> 2)) & 3;
            const unsigned short* g = (p ? sl2 : sh) + (long)(row0 + r) * 512 + k0 + (sl ^ fs) * 8;
            gload16(g, &sB[buf][p][r * 32 + sl * 8]);
        }
    };
    auto stage_A = [&](int buf, int k0) {
        if (tid < 128) {
            const int p = tid >> 6, c = tid & 63, r = c >> 2, sl = c & 3;
            const int fs = (r + (r >> 2)) & 3;
            const unsigned short* g = (p ? Al : Ah) + (long)r * 512 + k0 + (sl ^ fs) * 8;
            gload16(g, &sA[buf][p][r * 32 + sl * 8]);
        }
    };

    f32x4 acc[4];
#pragma unroll
    for (int i = 0; i < 4; i++) acc[i] = f32x4{0.f, 0.f, 0.f, 0.f};

    stage_B(0, xh, xl, 0, 0);
    stage_A(0, 0);
    __syncthreads();
    int buf = 0;
    const int fsa = (li + (li >> 2)) & 3;
    for (int t = 0; t < 32; t++) {
        const int half = t >> 4;
        const int nt = t + 1;
        if (nt < 32) {
            stage_B(buf ^ 1, xh, xl, (nt >> 4) * 256, (nt & 15) * 32);
            stage_A(buf ^ 1, (nt & 15) * 32);
        }
        bf16x8 ah = bc16(&sA[buf][0][li * 32 + ((ks ^ fsa)) * 8]);
        bf16x8 al = bc16(&sA[buf][1][li * 32 + ((ks ^ fsa)) * 8]);
        bf16x8 bh[2], bl[2];
#pragma unroll
        for (int ni = 0; ni < 2; ni++) {
            const int r = w * 32 + ni * 16 + li;
            const int fs = (r + (r >> 2)) & 3;
            bh[ni] = bc16(&sB[buf][0][r * 32 + ((ks ^ fs)) * 8]);
            bl[ni] = bc16(&sB[buf][1][r * 32 + ((ks ^ fs)) * 8]);
        }
#pragma unroll
        for (int ni = 0; ni < 2; ni++) acc[half * 2 + ni] = mfma16(ah, bh[ni], acc[half * 2 + ni]);
#pragma unroll
        for (int ni = 0; ni < 2; ni++) acc[half * 2 + ni] = mfma16(ah, bl[ni], acc[half * 2 + ni]);
#pragma unroll
        for (int ni = 0; ni < 2; ni++) acc[half * 2 + ni] = mfma16(al, bh[ni], acc[half * 2 + ni]);
        __syncthreads();
        buf ^= 1;
    }

    stage_B(buf, xTh, xTl, 0, 0);

    float M[4], S[4];
#pragma unroll
    for (int r4 = 0; r4 < 4; r4++) {
        float m = acc[0][r4];
#pragma unroll
        for (int i = 1; i < 4; i++) m = fmaxf(m, acc[i][r4]);
#pragma unroll
        for (int o = 1; o < 16; o <<= 1) m = fmaxf(m, __shfl_xor(m, o));
        M[r4] = m;
    }
    if (li == 0) {
#pragma unroll
        for (int r4 = 0; r4 < 4; r4++) redm[w][ks * 4 + r4] = M[r4];
    }
    __syncthreads();
#pragma unroll
    for (int r4 = 0; r4 < 4; r4++) {
        float m = redm[0][ks * 4 + r4];
#pragma unroll
        for (int ww = 1; ww < 8; ww++) m = fmaxf(m, redm[ww][ks * 4 + r4]);
        M[r4] = m;
    }
#pragma unroll
    for (int i = 0; i < 4; i++)
#pragma unroll
        for (int r4 = 0; r4 < 4; r4++) acc[i][r4] = expf(acc[i][r4] - M[r4]);
#pragma unroll
    for (int r4 = 0; r4 < 4; r4++) {
        float s = 0.f;
#pragma unroll
        for (int i = 0; i < 4; i++) s += acc[i][r4];
#pragma unroll
        for (int o = 1; o < 16; o <<= 1) s += __shfl_xor(s, o);
        S[r4] = s;
    }
    if (li == 0) {
#pragma unroll
        for (int r4 = 0; r4 < 4; r4++) reds[w][ks * 4 + r4] = S[r4];
    }
    __syncthreads();
#pragma unroll
    for (int r4 = 0; r4 < 4; r4++) {
        float s = 0.f;
#pragma unroll
        for (int ww = 0; ww < 8; ww++) s += reds[ww][ks * 4 + r4];
        S[r4] = 1.f / s;
    }
#pragma unroll
    for (int i = 0; i < 4; i++) {
        const int hf = i >> 1, ni = i & 1;
        const int s = hf * 256 + w * 32 + ni * 16 + li;
        const int kt = s >> 5, kks = (s >> 3) & 3, j = s & 7;
#pragma unroll
        for (int r4 = 0; r4 < 4; r4++) {
            const int row = ks * 4 + r4;
            const int fs = (row + (row >> 2)) & 3;
            unsigned short h, l2; split2(acc[i][r4] * S[r4], h, l2);
            sP[0][kt][row][(kks ^ fs) * 8 + j] = h;
            sP[1][kt][row][(kks ^ fs) * 8 + j] = l2;
        }
    }
    __syncthreads();

    f32x4 acc2[4];
#pragma unroll
    for (int i = 0; i < 4; i++) acc2[i] = f32x4{0.f, 0.f, 0.f, 0.f};
    for (int t = 0; t < 32; t++) {
        const int half = t >> 4, kt = t & 15;
        const int nt = t + 1;
        if (nt < 32) stage_B(buf ^ 1, xTh, xTl, (nt >> 4) * 256, (nt & 15) * 32);
        bf16x8 ph = bc16(&sP[0][kt][li][(ks ^ fsa) * 8]);
        bf16x8 pl = bc16(&sP[1][kt][li][(ks ^ fsa) * 8]);
        bf16x8 bh[2], bl[2];
#pragma unroll
        for (int ni = 0; ni < 2; ni++) {
            const int r = w * 32 + ni * 16 + li;
            const int fs = (r + (r >> 2)) & 3;
            bh[ni] = bc16(&sB[buf][0][r * 32 + ((ks ^ fs)) * 8]);
            bl[ni] = bc16(&sB[buf][1][r * 32 + ((ks ^ fs)) * 8]);
        }
#pragma unroll
        for (int ni = 0; ni < 2; ni++) acc2[half * 2 + ni] = mfma16(ph, bh[ni], acc2[half * 2 + ni]);
#pragma unroll
        for (int ni = 0; ni < 2; ni++) acc2[half * 2 + ni] = mfma16(ph, bl[ni], acc2[half * 2 + ni]);
#pragma unroll
        for (int ni = 0; ni < 2; ni++) acc2[half * 2 + ni] = mfma16(pl, bh[ni], acc2[half * 2 + ni]);
        __syncthreads();
        buf ^= 1;
    }

#pragma unroll
    for (int i = 0; i < 4; i++) {
        const int hf = i >> 1, ni = i & 1;
        const int n = hf * 256 + w * 32 + ni * 16 + li;
#pragma unroll
        for (int r4 = 0; r4 < 4; r4++) {
            const int m = r0 + ks * 4 + r4;
            const long id = ((long)b * 4 + (m & 3)) * 4096 + (long)(m >> 2) * 512 + n;
            unsigned short h, l2; split2(acc2[i][r4], h, l2);
            U_h[id] = h; U_l[id] = l2;
        }
    }
}

// ---------------------------------------------------------------------------
// Fused FFN, fine-grained: block (cx in [0,32) = 64-col f1 chunk, by = 16-row
// block). GEMM1: f1c[16x64] = q @ W1T-chunk (K=512). GELU+split -> sF.
// GEMM2: partial[cx] = f1c @ W2T[:, cx*64..+64) (K=64, N=512). np=32 partials.
// ---------------------------------------------------------------------------
__global__ __launch_bounds__(256)
void ffn_fused(const unsigned short* __restrict__ q_h, const unsigned short* __restrict__ q_l,
               const unsigned short* __restrict__ W1T_h, const unsigned short* __restrict__ W1T_l,
               const float* __restrict__ b1,
               const unsigned short* __restrict__ W2T_h, const unsigned short* __restrict__ W2T_l,
               float* __restrict__ parts)
{
    __shared__ __align__(16) unsigned short sA[2 * 1024];
    __shared__ __align__(16) unsigned short sB[2 * 4096];
    __shared__ __align__(16) unsigned short sB2[8192];
    __shared__ __align__(16) unsigned short sF[2][2][16][32];
    const int cx = blockIdx.x, m0 = blockIdx.y * 16;
    const int tid = threadIdx.x, lane = tid & 63, w = tid >> 6;
    const int li = lane & 15, ks = lane >> 4;
    const int n0 = cx * 64;

    auto stageB1 = [&](int buf, int k0) {
#pragma unroll
        for (int i = 0; i < 2; i++) {
            const int c = tid + 256 * i;
            const int p = c >> 8, cc = c & 255, r = cc >> 2, sl = cc & 3;
            const int fs = (r + (r >> 2)) & 3;
            const unsigned short* g = (p ? W1T_l : W1T_h) + (long)(n0 + r) * 512 + k0 + (sl ^ fs) * 8;
            gload16(g, sB + buf * 4096 + p * 2048 + r * 32 + sl * 8);
        }
    };
    auto stageA1 = [&](int buf, int k0) {
        if (tid < 128) {
            const int p = tid >> 6, c = tid & 63, r = c >> 2, sl = c & 3;
            const int fs = (r + (r >> 2)) & 3;
            const unsigned short* g = (p ? q_l : q_h) + (long)(m0 + r) * 512 + k0 + (sl ^ fs) * 8;
            gload16(g, sA + buf * 1024 + p * 512 + r * 32 + sl * 8);
        }
    };

    f32x4 acc = f32x4{0.f, 0.f, 0.f, 0.f};
    int buf = 0;
    stageB1(0, 0); stageA1(0, 0);
    __syncthreads();
    const int fsa = (li + (li >> 2)) & 3;
    for (int kt = 0; kt < 16; kt++) {
        if (kt + 1 < 16) { stageB1(buf ^ 1, (kt + 1) * 32); stageA1(buf ^ 1, (kt + 1) * 32); }
        bf16x8 ah = bc16(sA + buf * 1024 + li * 32 + ((ks ^ fsa)) * 8);
        bf16x8 al = bc16(sA + buf * 1024 + 512 + li * 32 + ((ks ^ fsa)) * 8);
        const int r = w * 16 + li;
        const int fs = (r + (r >> 2)) & 3;
        bf16x8 bh = bc16(sB + buf * 4096 + r * 32 + ((ks ^ fs)) * 8);
        bf16x8 bl = bc16(sB + buf * 4096 + 2048 + r * 32 + ((ks ^ fs)) * 8);
        acc = mfma16(ah, bh, acc);
        acc = mfma16(ah, bl, acc);
        acc = mfma16(al, bh, acc);
        __syncthreads();
        buf ^= 1;
    }

#pragma unroll
    for (int r4 = 0; r4 < 4; r4++) {
        const int row = ks * 4 + r4;
        const int fs = (row + (row >> 2)) & 3;
        const int n = w * 16 + li;
        float v = acc[r4] + b1[n0 + n];
        v = 0.5f * v * (1.f + erff(v * 0.70710678118654752f));
        const int kt = n >> 5, kks = (n >> 3) & 3, j = n & 7;
        unsigned short h, l2; split2(v, h, l2);
        sF[0][kt][row][(kks ^ fs) * 8 + j] = h;
        sF[1][kt][row][(kks ^ fs) * 8 + j] = l2;
    }
    __syncthreads();

    for (int nc = 0; nc < 4; nc++) {
        f32x4 acc2[2];
#pragma unroll
        for (int j = 0; j < 2; j++) acc2[j] = f32x4{0.f, 0.f, 0.f, 0.f};
        for (int kt2 = 0; kt2 < 2; kt2++) {
            __syncthreads();
#pragma unroll
            for (int i = 0; i < 4; i++) {
                const int c = tid + 256 * i;
                const int p = c >> 9, cc = c & 511, r = cc >> 2, sl = cc & 3;
                const int fs = (r + (r >> 2)) & 3;
                const unsigned short* g = (p ? W2T_l : W2T_h)
                    + (long)(nc * 128 + r) * 2048 + cx * 64 + kt2 * 32 + (sl ^ fs) * 8;
                gload16(g, sB2 + p * 4096 + r * 32 + sl * 8);
            }
            __syncthreads();
            bf16x8 fh, fl, bh[2], bl[2];
            {
                const int row = li;
                const int fs = (row + (row >> 2)) & 3;
                fh = bc16(&sF[0][kt2][row][(ks ^ fs) * 8]);
                fl = bc16(&sF[1][kt2][row][(ks ^ fs) * 8]);
            }
#pragma unroll
            for (int ni = 0; ni < 2; ni++) {
                const int r = w * 32 + ni * 16 + li;
                const int fs = (r + (r >> 2)) & 3;
                bh[ni] = bc16(sB2 + r * 32 + (ks ^ fs) * 8);
                bl[ni] = bc16(sB2 + 4096 + r * 32 + (ks ^ fs) * 8);
            }
#pragma unroll
            for (int ni = 0; ni < 2; ni++) acc2[ni] = mfma16(fh, bh[ni], acc2[ni]);
#pragma unroll
            for (int ni = 0; ni < 2; ni++) acc2[ni] = mfma16(fh, bl[ni], acc2[ni]);
#pragma unroll
            for (int ni = 0; ni < 2; ni++) acc2[ni] = mfma16(fl, bh[ni], acc2[ni]);
        }
#pragma unroll
        for (int r4 = 0; r4 < 4; r4++) {
            const int m = m0 + ks * 4 + r4;
#pragma unroll
            for (int ni = 0; ni < 2; ni++) {
                const int n2 = nc * 128 + w * 32 + ni * 16 + li;
                parts[(long)cx * 131072 + (long)m * 512 + n2] = acc2[ni][r4];
            }
        }
    }
}

// ===========================================================================
// Prep bodies + merged prep kernels
// ===========================================================================

__device__ void prepT_body(float* t, int bx, int by, int z,
                           const float* __restrict__ in,
                           unsigned short* __restrict__ Th, unsigned short* __restrict__ Tl,
                           int ldin, int ldo, long inStride, long outStride)
{
    const int n0 = bx * 64, k0 = by * 64;
    const int tid = threadIdx.x;
    const float* src = in + (long)z * inStride;
#pragma unroll
    for (int i = 0; i < 4; i++) {
        int ch = tid + 256 * i;
        int r = ch >> 4, q = ch & 15;
        float4 v = *(const float4*)(src + (long)(k0 + r) * ldin + n0 + q * 4);
        t[r * 68 + q * 4 + 0] = v.x; t[r * 68 + q * 4 + 1] = v.y;
        t[r * 68 + q * 4 + 2] = v.z; t[r * 68 + q * 4 + 3] = v.w;
    }
    __syncthreads();
#pragma unroll
    for (int i = 0; i < 4; i++) {
        int ch = tid + 256 * i;
        int rc = ch >> 4, qk = ch & 15;
        union { uint2 v; unsigned short u[4]; } oh, ol;
#pragma unroll
        for (int j = 0; j < 4; j++) split2(t[(qk * 4 + j) * 68 + rc], oh.u[j], ol.u[j]);
        long o = (long)z * outStride + (long)(n0 + rc) * ldo + k0 + qk * 4;
        *(uint2*)(Th + o) = oh.v;
        *(uint2*)(Tl + o) = ol.v;
    }
}

__device__ void t32_body(float* t, int bx, int by, int z,
                         const float* __restrict__ in, float* __restrict__ out, long zstr)
{
    const int c0 = bx * 64, r0 = by * 64;
    const int tid = threadIdx.x;
#pragma unroll
    for (int i = 0; i < 4; i++) {
        int ch = tid + 256 * i;
        int r = ch >> 4, q = ch & 15;
        float4 v = *(const float4*)(in + (long)z * zstr + (long)(r0 + r) * 512 + c0 + q * 4);
        t[r * 65 + q * 4 + 0] = v.x; t[r * 65 + q * 4 + 1] = v.y;
        t[r * 65 + q * 4 + 2] = v.z; t[r * 65 + q * 4 + 3] = v.w;
    }
    __syncthreads();
#pragma unroll
    for (int i = 0; i < 4; i++) {
        int ch = tid + 256 * i;
        int rc = ch >> 4, qk = ch & 15;
        float4 o;
        o.x = t[(qk * 4 + 0) * 65 + rc]; o.y = t[(qk * 4 + 1) * 65 + rc];
        o.z = t[(qk * 4 + 2) * 65 + rc]; o.w = t[(qk * 4 + 3) * 65 + rc];
        *(float4*)(out + (long)z * zstr + (long)(c0 + rc) * 512 + r0 + qk * 4) = o;
    }
}

__global__ __launch_bounds__(256)
void big_prep(const float* projW, unsigned short* pwT_h, unsigned short* pwT_l,
              const float* W1, unsigned short* W1T_h, unsigned short* W1T_l,
              const float* W2, unsigned short* W2T_h, unsigned short* W2T_l,
              const float* Wo, float* WoT)
{
    __shared__ float t[64 * 68];
    const int bid = blockIdx.x;
    if (bid < 128) {
        prepT_body(t, bid & 7, bid >> 3, 0, projW, pwT_h, pwT_l, 512, 1024, 0, 0);
    } else if (bid < 1152) {
        int u = bid - 128;
        prepT_body(t, u & 31, (u >> 5) & 7, u >> 8, W1, W1T_h, W1T_l, 2048, 512, 1048576, 1048576);
    } else if (bid < 2176) {
        int u = bid - 1152;
        prepT_body(t, u & 7, (u >> 3) & 31, u >> 8, W2, W2T_h, W2T_l, 512, 2048, 1048576, 1048576);
    } else {
        int u = bid - 2176;
        t32_body(t, u & 7, (u >> 3) & 7, u >> 6, Wo, WoT, 262144);
    }
}

__device__ void w2_body(unsigned short* sA, unsigned short* sB, int bx, int by, int z,
                        const float* A_, const float* B_, float scale,
                        unsigned short* Th, unsigned short* Tl,
                        long zsA, long zsB, long S1, long S2, long SMs)
{
    const int tid = threadIdx.x;
    const int m0 = by * 128, n0 = bx * 128;
    const int lane = tid & 63, w = tid >> 6, wr = w >> 1, wc = w & 1;
    const float* Ab = A_ + (long)(z >> 3) * zsA + (z & 7) * 64;
    const float* Bb = B_ + (long)(z >> 3) * zsB + (z & 7) * 64;

    f32x4 acc[4][4];
#pragma unroll
    for (int i = 0; i < 4; i++)
#pragma unroll
        for (int j = 0; j < 4; j++) acc[i][j] = f32x4{0.f, 0.f, 0.f, 0.f};

    for (int k0 = 0; k0 < 64; k0 += 32) {
        __syncthreads();
#pragma unroll
        for (int op = 0; op < 2; op++) {
            const float* src0 = op ? Bb : Ab;
            unsigned short* dst = op ? sB : sA;
#pragma unroll
            for (int i = 0; i < 2; i++) {
                const int c = tid + 256 * i;
                const int r = c >> 2, s = c & 3;
                const int fs = (r + (r >> 2)) & 3;
                const float* src = src0 + (long)((op ? n0 : m0) + r) * 512 + k0 + s * 8;
                float4 v0 = *(const float4*)src;
                float4 v1 = *(const float4*)(src + 4);
                float vv[8] = {v0.x, v0.y, v0.z, v0.w, v1.x, v1.y, v1.z, v1.w};
                union { s16x8 v; unsigned short u[8]; } hh, ll;
#pragma unroll
                for (int j = 0; j < 8; j++) split2(vv[j], hh.u[j], ll.u[j]);
                *(s16x8*)&dst[0 * 4096 + r * 32 + (s ^ fs) * 8] = hh.v;
                *(s16x8*)&dst[1 * 4096 + r * 32 + (s ^ fs) * 8] = ll.v;
            }
        }
        __syncthreads();
        const int li = lane & 15, ks = lane >> 4;
        bf16x8 ah[4], al[4], bh[4], bl[4];
#pragma unroll
        for (int mi = 0; mi < 4; mi++) {
            const int r = wr * 64 + mi * 16 + li;
            const int fs = (r + (r >> 2)) & 3;
            ah[mi] = bc16(sA + r * 32 + (ks ^ fs) * 8);
            al[mi] = bc16(sA + 4096 + r * 32 + (ks ^ fs) * 8);
        }
#pragma unroll
        for (int ni = 0; ni < 4; ni++) {
            const int r = wc * 64 + ni * 16 + li;
            const int fs = (r + (r >> 2)) & 3;
            bh[ni] = bc16(sB + r * 32 + (ks ^ fs) * 8);
            bl[ni] = bc16(sB + 4096 + r * 32 + (ks ^ fs) * 8);
        }
#pragma unroll
        for (int mi = 0; mi < 4; mi++)
#pragma unroll
            for (int ni = 0; ni < 4; ni++) acc[mi][ni] = mfma16(ah[mi], bh[ni], acc[mi][ni]);
#pragma unroll
        for (int mi = 0; mi < 4; mi++)
#pragma unroll
            for (int ni = 0; ni < 4; ni++) acc[mi][ni] = mfma16(ah[mi], bl[ni], acc[mi][ni]);
#pragma unroll
        for (int mi = 0; mi < 4; mi++)
#pragma unroll
            for (int ni = 0; ni < 4; ni++) acc[mi][ni] = mfma16(al[mi], bh[ni], acc[mi][ni]);
    }
#pragma unroll
    for (int mi = 0; mi < 4; mi++)
#pragma unroll
        for (int r4 = 0; r4 < 4; r4++) {
            const int m = m0 + wr * 64 + mi * 16 + (lane >> 4) * 4 + r4;
#pragma unroll
            for (int ni = 0; ni < 4; ni++) {
                const int n = n0 + wc * 64 + ni * 16 + (lane & 15);
                float v = acc[mi][ni][r4] * scale;
                unsigned short h, l; split2(v, h, l);
                long id = (long)(z >> 3) * S1 + (long)(z & 7) * S2 + (long)m * SMs + n;
                Th[id] = h; Tl[id] = l;
            }
        }
}

__global__ __launch_bounds__(256)
void w2_merged(const float* Wk, const float* Wq,
               unsigned short* MT_h, unsigned short* MT_l,
               const float* WoT, const float* Wv,
               unsigned short* WVOT_h, unsigned short* WVOT_l)
{
    __shared__ __align__(16) unsigned short sA[2 * 4096];
    __shared__ __align__(16) unsigned short sB[2 * 4096];
    const int bid = blockIdx.x;
    if (bid < 512) {
        w2_body(sA, sB, bid & 3, (bid >> 2) & 3, bid >> 4, Wk, Wq, 0.125f, MT_h, MT_l,
                262144, 262144, 2097152, 262144, 512);
    } else {
        int u = bid - 512;
        w2_body(sA, sB, u & 3, (u >> 2) & 3, u >> 4, WoT, Wv, 1.f, WVOT_h, WVOT_l,
                262144, 262144, 2097152, 512, 4096);
    }
}

__global__ __launch_bounds__(256)
void small_prep(const float* cbook, float* cbT, float* cn,
                const float* bq, const float* Wk, float* biasA,
                const float* bv, const float* Wo, const float* bo, float* biasO,
                const float* qt, float* q, unsigned short* qh_s, unsigned short* ql_s)
{
    __shared__ float sm[256];
    const int bid = blockIdx.x, tid = threadIdx.x;
    if (bid < 768) {
        const int rowi = bid, l = rowi >> 8, j = rowi & 255;
        const float* row = cbook + (long)rowi * 512;
        float v0 = row[tid], v1 = row[tid + 256];
        cbT[(long)l * 131072 + (long)tid * 256 + j]         = v0;
        cbT[(long)l * 131072 + (long)(tid + 256) * 256 + j] = v1;
        float s = v0 * v0 + v1 * v1;
#pragma unroll
        for (int o = 32; o > 0; o >>= 1) s += __shfl_xor(s, o);
        if ((tid & 63) == 0) sm[tid >> 6] = s;
        __syncthreads();
        if (tid == 0) cn[rowi] = sm[0] + sm[1] + sm[2] + sm[3];
    } else if (bid < 832) {
        const int gid = (bid - 768) * 256 + tid;
        const int l = gid >> 12, hc = gid & 4095, h = hc >> 9, c = hc & 511;
        const float* b = bq + l * 512 + h * 64;
        const float* w = Wk + (long)l * 262144 + (long)c * 512 + h * 64;
        float s = 0.f;
#pragma unroll 16
        for (int d = 0; d < 64; d++) s = fmaf(b[d], w[d], s);
        biasA[gid] = 0.125f * s;
    } else if (bid < 864) {
        const int u = bid - 832;
        const int l = u >> 3, oc = u & 7;
        const int o = oc * 64 + (tid & 63), j4 = tid >> 6;
        float acc = 0.f;
        for (int j = j4; j < 512; j += 4)
            acc = fmaf(bv[l * 512 + j], Wo[(long)l * 262144 + (long)j * 512 + o], acc);
        sm[j4 * 64 + (tid & 63)] = acc;
        __syncthreads();
        if (tid < 64) {
            float s = sm[tid] + sm[64 + tid] + sm[128 + tid] + sm[192 + tid]
                    + bo[l * 512 + oc * 64 + tid];
            biasO[l * 512 + oc * 64 + tid] = s;
        }
    } else {
        const int r = bid - 864, t = r & 3;
        const long base = (long)r * 512;
        float a = qt[t * 512 + tid], c = qt[t * 512 + 256 + tid];
        q[base + tid] = a; q[base + 256 + tid] = c;
        unsigned short h, l;
        split2(a, h, l); qh_s[base + tid] = h;       ql_s[base + tid] = l;
        split2(c, h, l); qh_s[base + tid + 256] = h; ql_s[base + tid + 256] = l;
    }
}

// ---- x hi/lo [b*s][c] -> xT hi/lo [b][c][s] --------------------------------
__global__ __launch_bounds__(256) void transpose_x(const unsigned short* __restrict__ xh,
                                                   const unsigned short* __restrict__ xl,
                                                   unsigned short* __restrict__ xTh,
                                                   unsigned short* __restrict__ xTl)
{
    __shared__ unsigned short th[64][72], tl[64][72];
    const int b = blockIdx.z, c0 = blockIdx.x * 64, s0 = blockIdx.y * 64;
    const int tid = threadIdx.x;
    const long ibase = ((long)b * 512 + s0) * 512 + c0;
#pragma unroll
    for (int i = 0; i < 2; i++) {
        int ch = tid + 256 * i;
        int r = ch >> 3, s = ch & 7;
        *(s16x8*)&th[r][s * 8] = *(const s16x8*)(xh + ibase + (long)r * 512 + s * 8);
        *(s16x8*)&tl[r][s * 8] = *(const s16x8*)(xl + ibase + (long)r * 512 + s * 8);
    }
    __syncthreads();
    const long obase = ((long)b * 512 + c0) * 512 + s0;
#pragma unroll
    for (int i = 0; i < 2; i++) {
        int ch = tid + 256 * i;
        int rc = ch >> 3, sc = ch & 7;
        union { s16x8 v; unsigned short u[8]; } oh, ol;
#pragma unroll
        for (int j = 0; j < 8; j++) { oh.u[j] = th[sc * 8 + j][rc]; ol.u[j] = tl[sc * 8 + j][rc]; }
        *(s16x8*)(xTh + obase + (long)rc * 512 + sc * 8) = oh.v;
        *(s16x8*)(xTl + obase + (long)rc * 512 + sc * 8) = ol.v;
    }
}

// ---- q = LayerNorm(q + sum_z parts[z] + bias)*g + b; emit split q ----------
__global__ __launch_bounds__(256) void add_ln_sum(float* __restrict__ q,
                                                  const float* __restrict__ parts, int np,
                                                  const float* __restrict__ bias,
                                                  const float* __restrict__ g,
                                                  const float* __restrict__ b,
                                                  unsigned short* __restrict__ qh_s,
                                                  unsigned short* __restrict__ ql_s)
{
    __shared__ float red[4];
    const int tid = threadIdx.x;
    const long base = (long)blockIdx.x * 512;
    float* row = q + base;
    float v0 = row[tid] + bias[tid];
    float v1 = row[tid + 256] + bias[tid + 256];
    for (int z = 0; z < np; z++) {
        v0 += parts[(long)z * 131072 + base + tid];
        v1 += parts[(long)z * 131072 + base + tid + 256];
    }
    float s = v0 + v1;
#pragma unroll
    for (int o = 32; o > 0; o >>= 1) s += __shfl_xor(s, o);
    if ((tid & 63) == 0) red[tid >> 6] = s;
    __syncthreads();
    float mu = (red[0] + red[1] + red[2] + red[3]) * (1.f / 512.f);
    __syncthreads();
    float c0 = v0 - mu, c1 = v1 - mu;
    float sq = c0 * c0 + c1 * c1;
#pragma unroll
    for (int o = 32; o > 0; o >>= 1) sq += __shfl_xor(sq, o);
    if ((tid & 63) == 0) red[tid >> 6] = sq;
    __syncthreads();
    float var = (red[0] + red[1] + red[2] + red[3]) * (1.f / 512.f);
    float rs = rsqrtf(var + 1e-5f);
    float o0 = c0 * rs * g[tid] + b[tid];
    float o1 = c1 * rs * g[tid + 256] + b[tid + 256];
    row[tid] = o0; row[tid + 256] = o1;
    unsigned short h, l;
    split2(o0, h, l); qh_s[base + tid] = h;       ql_s[base + tid] = l;
    split2(o1, h, l); qh_s[base + tid + 256] = h; ql_s[base + tid + 256] = l;
}

__global__ __launch_bounds__(256) void rq_kernel(const float* __restrict__ qf,
                                                 const float* __restrict__ cb,
                                                 const float* __restrict__ cbT,
                                                 const float* __restrict__ cn,
                                                 float* __restrict__ out)
{
    __shared__ float r[512], rec[512];
    __shared__ float rd[4]; __shared__ int ri[4];
    __shared__ int sids[3];
    const int p = blockIdx.x, tid = threadIdx.x;
    r[tid]         = qf[(long)p * 512 + tid];
    r[tid + 256]   = qf[(long)p * 512 + 256 + tid];
    rec[tid] = 0.f; rec[tid + 256] = 0.f;
    __syncthreads();
    for (int l = 0; l < 3; l++) {
        const float* ct = cbT + (long)l * 131072;
        float dot = 0.f;
#pragma unroll 8
        for (int k = 0; k < 512; k++) dot = fmaf(r[k], ct[(long)k * 256 + tid], dot);
        float d2 = cn[l * 256 + tid] - 2.f * dot;
        int idx = tid;
#pragma unroll
        for (int o = 32; o > 0; o >>= 1) {
            float od = __shfl_xor(d2, o); int oi = __shfl_xor(idx, o);
            if (od < d2 || (od == d2 && oi < idx)) { d2 = od; idx = oi; }
        }
        if ((tid & 63) == 0) { rd[tid >> 6] = d2; ri[tid >> 6] = idx; }
        __syncthreads();
        if (tid == 0) {
            float bd = rd[0]; int bb = ri[0];
            for (int w = 1; w < 4; w++)
                if (rd[w] < bd || (rd[w] == bd && ri[w] < bb)) { bd = rd[w]; bb = ri[w]; }
            sids[l] = bb;
        }
        __syncthreads();
        const float* crow = cb + ((long)l * 256 + sids[l]) * 512;
        float c0 = crow[tid], c1 = crow[tid + 256];
        r[tid] -= c0; rec[tid] += c0;
        r[tid + 256] -= c1; rec[tid + 256] += c1;
        __syncthreads();
    }
    float* orec = out + 768 + (long)p * 512;
    orec[tid] = rec[tid]; orec[tid + 256] = rec[tid + 256];
    if (tid < 3) out[p * 3 + tid] = (float)sids[tid];
}

// ---------------------------------------------------------------------------
extern "C" void kernel_launch(void* const* d_in, const int* in_sizes, int n_in,
                              void* d_out, int out_size, void* d_ws, size_t ws_size,
                              hipStream_t stream)
{
    const float* mm    = (const float*)d_in[0];
    const float* projW = (const float*)d_in[1];
    const float* projb = (const float*)d_in[2];
    const float* qt    = (const float*)d_in[3];
    const float* Wq    = (const float*)d_in[4];
    const float* bq    = (const float*)d_in[5];
    const float* Wk    = (const float*)d_in[6];
    const float* Wv    = (const float*)d_in[8];
    const float* bv    = (const float*)d_in[9];
    const float* Wo    = (const float*)d_in[10];
    const float* bo    = (const float*)d_in[11];
    const float* W1    = (const float*)d_in[12];
    const float* b1    = (const float*)d_in[13];
    const float* W2    = (const float*)d_in[14];
    const float* b2    = (const float*)d_in[15];
    const float* lng   = (const float*)d_in[16];
    const float* lnb   = (const float*)d_in[17];
    const float* cbook = (const float*)d_in[18];

    char* p = (char*)d_ws;
    auto alloc = [&](size_t bytes) { char* r = p; p += (bytes + 255) & ~(size_t)255; return r; };
    unsigned short* x_h   = (unsigned short*)alloc(16777216ull * 2);
    unsigned short* x_l   = (unsigned short*)alloc(16777216ull * 2);
    unsigned short* xT_h  = (unsigned short*)alloc(16777216ull * 2);
    unsigned short* xT_l  = (unsigned short*)alloc(16777216ull * 2);
    unsigned short* pwT_h = (unsigned short*)alloc(524288ull * 2);
    unsigned short* pwT_l = (unsigned short*)alloc(524288ull * 2);
    unsigned short* MT_h  = (unsigned short*)alloc(8388608ull * 2);
    unsigned short* MT_l  = (unsigned short*)alloc(8388608ull * 2);
    unsigned short* WVOT_h= (unsigned short*)alloc(8388608ull * 2);
    unsigned short* WVOT_l= (unsigned short*)alloc(8388608ull * 2);
    float*          WoT   = (float*)alloc(1048576ull * 4);
    unsigned short* W1T_h = (unsigned short*)alloc(4194304ull * 2);
    unsigned short* W1T_l = (unsigned short*)alloc(4194304ull * 2);
    unsigned short* W2T_h = (unsigned short*)alloc(4194304ull * 2);
    unsigned short* W2T_l = (unsigned short*)alloc(4194304ull * 2);
    unsigned short* A_h   = (unsigned short*)alloc(1048576ull * 2);
    unsigned short* A_l   = (unsigned short*)alloc(1048576ull * 2);
    unsigned short* U_h   = (unsigned short*)alloc(1048576ull * 2);
    unsigned short* U_l   = (unsigned short*)alloc(1048576ull * 2);
    unsigned short* q_h   = (unsigned short*)alloc(131072ull * 2);
    unsigned short* q_l   = (unsigned short*)alloc(131072ull * 2);
    float* parts = (float*)alloc(32ull * 131072 * 4);
    float* q     = (float*)alloc(131072ull * 4);
    float* cbT   = (float*)alloc(393216ull * 4);
    float* cn    = (float*)alloc(768ull * 4);
    float* biasA = (float*)alloc(16384ull * 4);
    float* biasO = (float*)alloc(2048ull * 4);

    // ---- merged one-time preps (3 dispatches) ----
    big_prep<<<2432, 256, 0, stream>>>(projW, pwT_h, pwT_l, W1, W1T_h, W1T_l,
                                       W2, W2T_h, W2T_l, Wo, WoT);
    w2_merged<<<1024, 256, 0, stream>>>(Wk, Wq, MT_h, MT_l, WoT, Wv, WVOT_h, WVOT_l);
    small_prep<<<1120, 256, 0, stream>>>(cbook, cbT, cn, bq, Wk, biasA,
                                         bv, Wo, bo, biasO, qt, q, q_h, q_l);

    // ---- x = mm @ projW + projb (split out), then xT ----
    mfma_gemm<128, 4, 4, 2, 2, 1, 1, 0, false, true><<<dim3(4, 256, 1), 256, 0, stream>>>(
        mm, nullptr, pwT_h, pwT_l, projb, x_h, x_l, 1024, 1024, 1024, 512, 0, 0, 0);
    transpose_x<<<dim3(8, 8, 64), 256, 0, stream>>>(x_h, x_l, xT_h, xT_l);

    for (int i = 0; i < 4; i++) {
        const unsigned short* MTh = MT_h + (long)i * 2097152;
        const unsigned short* MTl = MT_l + (long)i * 2097152;
        const unsigned short* WVh = WVOT_h + (long)i * 2097152;
        const unsigned short* WVl = WVOT_l + (long)i * 2097152;
        const unsigned short* W1h = W1T_h + (long)i * 1048576;
        const unsigned short* W1l = W1T_l + (long)i * 1048576;
        const unsigned short* W2h = W2T_h + (long)i * 1048576;
        const unsigned short* W2l = W2T_l + (long)i * 1048576;
        const float* b1i = b1 + i * 2048; const float* b2i = b2 + i * 512;
        const float* gi  = lng + i * 512; const float* bi_ = lnb + i * 512;

        // A[b][ht][c] = q @ MT + biasA   (BM=16: 512 blocks, 2 waves/SIMD)
        mfma_gemm<16, 1, 2, 1, 4, 0, 1, 1, false, false><<<dim3(32, 16, 1), 256, 0, stream>>>(
            q_h, q_l, MTh, MTl, biasA + i * 4096, A_h, A_l, 512, 512, 512, 512, 0, 0, 0);
        // fused scores -> softmax -> U  (512 threads, XCD pair-swizzled)
        fused_attn<<<dim3(2, 64), 512, 0, stream>>>(A_h, A_l, x_h, x_l, xT_h, xT_l, U_h, U_l);
        // attn_out partials = U @ WVOT  (BM=16, split-K 8: 512 blocks)
        mfma_gemm<16, 1, 2, 1, 4, 0, 0, 0, false, false><<<dim3(4, 16, 8), 256, 0, stream>>>(
            U_h, U_l, WVh, WVl, nullptr, parts, nullptr, 512, 4096, 4096, 512,
            512, 512, 131072);
        add_ln_sum<<<256, 256, 0, stream>>>(q, parts, 8, biasO + i * 512, gi, bi_, q_h, q_l);
        // fused ffn1+ffn2 -> 32 partials (512 blocks)
        ffn_fused<<<dim3(32, 16), 256, 0, stream>>>(q_h, q_l, W1h, W1l, b1i, W2h, W2l, parts);
        add_ln_sum<<<256, 256, 0, stream>>>(q, parts, 32, b2i, gi, bi_, q_h, q_l);
    }

    rq_kernel<<<256, 256, 0, stream>>>(q, cbook, cbT, cn, (float*)d_out);
}